// Round 3
// baseline (10283.266 us; speedup 1.0000x reference)
//
#include <hip/hip_runtime.h>
#include <math.h>

typedef unsigned short u16;
typedef float f32x4 __attribute__((ext_vector_type(4)));
typedef short s16x8 __attribute__((ext_vector_type(8)));

#define D_MODEL 1024
#define NH 16
#define DK 64
#define DFF 4096
#define BB 4
#define SS 2048
#define ROWS (BB*SS)   // 8192
#define MiB 1048576ull
#define BHSZ 4194304ull   // floats per att[bh] block (2048*2048)
#define QKS  131072ull    // floats per bh slice of q/k (2048*64)

static __device__ __forceinline__ float bf2f(u16 v){
  union{unsigned u; float f;} x; x.u = ((unsigned)v)<<16; return x.f;
}
static __device__ __forceinline__ u16 f2bf(float f){
  union{float f; unsigned u;} x; x.f=f;
  unsigned r = x.u + 0x7fffu + ((x.u>>16)&1u);
  return (u16)(r>>16);
}
static __device__ __forceinline__ double softplus64(float gf){
  double g = (double)gf;
  return (g > 0.0) ? g + log1p(exp(-g)) : log1p(exp(g));
}

// -------------------------------------------------- transpose + f32->bf16 split
__global__ __launch_bounds__(256) void twc(const float* __restrict__ in,
    u16* __restrict__ oh, u16* __restrict__ om, u16* __restrict__ ol, int R, int C){
  __shared__ float t[32][33];
  int c0 = blockIdx.x*32, r0 = blockIdx.y*32;
  int tx = threadIdx.x & 31, ty = threadIdx.x >> 5;
  for (int i=ty; i<32; i+=8) t[i][tx] = in[(size_t)(r0+i)*C + c0 + tx];
  __syncthreads();
  for (int i=ty; i<32; i+=8){
    float x = t[tx][i];
    u16 h = f2bf(x);
    size_t o = (size_t)(c0+i)*R + r0 + tx;
    oh[o] = h;
    if (om){
      float r1 = x - bf2f(h);
      u16 m = f2bf(r1);
      om[o] = m;
      if (ol){ float r2 = r1 - bf2f(m); ol[o] = f2bf(r2); }
    }
  }
}

// -------------------------------------------------- f32 copy
__global__ __launch_bounds__(256) void copyf(float* __restrict__ dst,
                                             const float* __restrict__ src, long long n){
  long long i = (long long)blockIdx.x*256 + threadIdx.x;
  long long stride = (long long)gridDim.x*256;
  for (; i < n; i += stride) dst[i] = src[i];
}

// -------------------------------------------------- triple-split GEMM (Q/K proj)
__global__ __launch_bounds__(256) void gemm3(
    const float* __restrict__ A, const u16* __restrict__ Bh,
    const u16* __restrict__ Bm, const u16* __restrict__ Bl,
    const float* __restrict__ bias, int M, int N, int K, float* __restrict__ o)
{
  __shared__ u16 lAh[128*32], lAm[128*32], lAl[128*32];
  __shared__ u16 lBh[128*32], lBm[128*32], lBl[128*32];
  const int tid = threadIdx.x, wid = tid>>6, L = tid&63;
  const int m0 = blockIdx.y*128, n0 = blockIdx.x*128;
  const int wm = (wid>>1)*64, wn = (wid&1)*64;
  f32x4 acc[4][4] = {};
  const int srow = wid*32 + (L>>2);
  const int scol = (L&3)*8;
  for (int kt=0; kt<K; kt+=32){
    s16x8 ah[2], am[2], al[2], vbh[2], vbm[2], vbl[2];
    #pragma unroll
    for (int rr=0; rr<2; rr++){
      const float* ap = &A[(size_t)(m0 + srow + rr*16)*K + kt + scol];
      #pragma unroll
      for (int e=0;e<8;e++){
        float x = ap[e];
        u16 hh = f2bf(x); float r1 = x - bf2f(hh);
        u16 mm = f2bf(r1); float r2 = r1 - bf2f(mm);
        ah[rr][e] = (short)hh; am[rr][e] = (short)mm; al[rr][e] = (short)f2bf(r2);
      }
      const size_t bo = (size_t)(n0 + srow + rr*16)*K + kt + scol;
      vbh[rr] = *(const s16x8*)&Bh[bo];
      vbm[rr] = *(const s16x8*)&Bm[bo];
      vbl[rr] = *(const s16x8*)&Bl[bo];
    }
    __syncthreads();
    #pragma unroll
    for (int rr=0; rr<2; rr++){
      const int ro = (srow + rr*16)*32 + scol;
      *(s16x8*)&lAh[ro] = ah[rr]; *(s16x8*)&lAm[ro] = am[rr]; *(s16x8*)&lAl[ro] = al[rr];
      *(s16x8*)&lBh[ro] = vbh[rr]; *(s16x8*)&lBm[ro] = vbm[rr]; *(s16x8*)&lBl[ro] = vbl[rr];
    }
    __syncthreads();
    const int lro = (L&15)*32 + (L>>4)*8;
    s16x8 afh[4], afm[4], afl[4], bfh[4], bfm[4], bfl[4];
    #pragma unroll
    for (int t=0;t<4;t++){
      afh[t] = *(const s16x8*)&lAh[(wm + t*16)*32 + lro];
      afm[t] = *(const s16x8*)&lAm[(wm + t*16)*32 + lro];
      afl[t] = *(const s16x8*)&lAl[(wm + t*16)*32 + lro];
      bfh[t] = *(const s16x8*)&lBh[(wn + t*16)*32 + lro];
      bfm[t] = *(const s16x8*)&lBm[(wn + t*16)*32 + lro];
      bfl[t] = *(const s16x8*)&lBl[(wn + t*16)*32 + lro];
    }
    #pragma unroll
    for (int mt=0;mt<4;mt++)
      #pragma unroll
      for (int nt=0;nt<4;nt++){
        f32x4 a2 = acc[mt][nt];
        a2 = __builtin_amdgcn_mfma_f32_16x16x32_bf16(afl[mt], bfh[nt], a2, 0,0,0);
        a2 = __builtin_amdgcn_mfma_f32_16x16x32_bf16(afm[mt], bfm[nt], a2, 0,0,0);
        a2 = __builtin_amdgcn_mfma_f32_16x16x32_bf16(afh[mt], bfl[nt], a2, 0,0,0);
        a2 = __builtin_amdgcn_mfma_f32_16x16x32_bf16(afm[mt], bfh[nt], a2, 0,0,0);
        a2 = __builtin_amdgcn_mfma_f32_16x16x32_bf16(afh[mt], bfm[nt], a2, 0,0,0);
        a2 = __builtin_amdgcn_mfma_f32_16x16x32_bf16(afh[mt], bfh[nt], a2, 0,0,0);
        acc[mt][nt] = a2;
      }
  }
  #pragma unroll
  for (int mt=0;mt<4;mt++)
    #pragma unroll
    for (int nt=0;nt<4;nt++){
      const int gn = n0 + wn + nt*16 + (L&15);
      const float bvv = bias[gn];
      const int gmb = m0 + wm + mt*16 + (L>>4)*4;
      const int h = gn>>6, d = gn&63;
      #pragma unroll
      for (int r=0;r<4;r++){
        const int gm = gmb + r, b = gm>>11, s = gm&2047;
        o[((size_t)(b*NH+h)*SS + s)*DK + d] = acc[mt][nt][r] + bvv;
      }
    }
}

// -------------------------------------------------- pair-split GEMM (~f32 quality)
__global__ __launch_bounds__(256) void gemm2(
    const float* __restrict__ A, const u16* __restrict__ Bh, const u16* __restrict__ Bl,
    const float* __restrict__ bias, int M, int N, int K, int mode, float* __restrict__ o)
{
  __shared__ u16 lAh[128*32], lAl[128*32], lBh[128*32], lBl[128*32];
  const int tid = threadIdx.x, wid = tid>>6, L = tid&63;
  const int m0 = blockIdx.y*128, n0 = blockIdx.x*128;
  const int wm = (wid>>1)*64, wn = (wid&1)*64;
  f32x4 acc[4][4] = {};
  const int srow = wid*32 + (L>>2);
  const int scol = (L&3)*8;
  for (int kt=0; kt<K; kt+=32){
    s16x8 ah[2], al[2], vbh[2], vbl[2];
    #pragma unroll
    for (int rr=0; rr<2; rr++){
      const float* ap = &A[(size_t)(m0 + srow + rr*16)*K + kt + scol];
      #pragma unroll
      for (int e=0;e<8;e++){
        float x = ap[e];
        u16 hh = f2bf(x);
        ah[rr][e] = (short)hh;
        al[rr][e] = (short)f2bf(x - bf2f(hh));
      }
      const size_t bo = (size_t)(n0 + srow + rr*16)*K + kt + scol;
      vbh[rr] = *(const s16x8*)&Bh[bo];
      vbl[rr] = *(const s16x8*)&Bl[bo];
    }
    __syncthreads();
    #pragma unroll
    for (int rr=0; rr<2; rr++){
      const int ro = (srow + rr*16)*32 + scol;
      *(s16x8*)&lAh[ro] = ah[rr]; *(s16x8*)&lAl[ro] = al[rr];
      *(s16x8*)&lBh[ro] = vbh[rr]; *(s16x8*)&lBl[ro] = vbl[rr];
    }
    __syncthreads();
    const int lro = (L&15)*32 + (L>>4)*8;
    s16x8 afh[4], afl[4], bfh[4], bfl[4];
    #pragma unroll
    for (int t=0;t<4;t++){
      afh[t] = *(const s16x8*)&lAh[(wm + t*16)*32 + lro];
      afl[t] = *(const s16x8*)&lAl[(wm + t*16)*32 + lro];
      bfh[t] = *(const s16x8*)&lBh[(wn + t*16)*32 + lro];
      bfl[t] = *(const s16x8*)&lBl[(wn + t*16)*32 + lro];
    }
    #pragma unroll
    for (int mt=0;mt<4;mt++)
      #pragma unroll
      for (int nt=0;nt<4;nt++){
        f32x4 a2 = acc[mt][nt];
        a2 = __builtin_amdgcn_mfma_f32_16x16x32_bf16(afl[mt], bfh[nt], a2, 0,0,0);
        a2 = __builtin_amdgcn_mfma_f32_16x16x32_bf16(afh[mt], bfl[nt], a2, 0,0,0);
        a2 = __builtin_amdgcn_mfma_f32_16x16x32_bf16(afh[mt], bfh[nt], a2, 0,0,0);
        acc[mt][nt] = a2;
      }
  }
  #pragma unroll
  for (int mt=0;mt<4;mt++)
    #pragma unroll
    for (int nt=0;nt<4;nt++){
      const int gn = n0 + wn + nt*16 + (L&15);
      const float bvv = bias[gn];
      const int gmb = m0 + wm + mt*16 + (L>>4)*4;
      #pragma unroll
      for (int r=0;r<4;r++){
        const int gm = gmb + r;
        float v = acc[mt][nt][r] + bvv;
        if (mode==0)      o[(size_t)gm*N + gn] = v;
        else if (mode==1) o[(size_t)gm*N + gn] = fmaxf(v, 0.f);
        else {
          const int b = gm>>11, s = gm&2047, h = gn>>6, d = gn&63;
          o[((size_t)(b*NH+h)*SS + s)*DK + d] = v;
        }
      }
    }
}

// -------------------------------------------------- attention row kernel (v4)
// f64 dot; eff(delta) via per-thread geometric recurrence (no LDS table):
//   u0 = exp(c*(i-t)), u *= exp(-256c) per step, eff = 0.125*min(u,1e5).
// LDS ~9.8 KB/block (was 26.6 KB) -> 5-6 blocks/CU residency.
// Score j-loop pair-unrolled so two dots share each sq ds_read.
__global__ __launch_bounds__(256) void attn_row(
  const float* __restrict__ q, const float* __restrict__ k, long long qs,
  int bh0, int row0,
  const float* __restrict__ vb, const float* __restrict__ gammas,
  float* __restrict__ att, float* __restrict__ ctx,
  int aw_lo, int aw_hi, int wc)
{
  __shared__ double sq[64];
  __shared__ float  p[SS];        // normalized probs (cross-thread)
  __shared__ double red[4];
  __shared__ float  cpart[4][64];
  const int i = row0 + blockIdx.x;
  const int bh = bh0 + blockIdx.y, h = bh&15, b = bh>>4;
  const int wa = (bh >= aw_lo) && (bh < aw_hi);
  const int t = threadIdx.x, wid = t>>6, L = t&63;
  const double c = softplus64(gammas[h]) * (1.0/21.0);

  if (t < 64) sq[t] = (double)q[(size_t)blockIdx.y*qs + (size_t)i*DK + t];
  double u = exp(c * (double)(i - t));     // decay state for this thread's j walk
  const double step = exp(-256.0 * c);
  __syncthreads();

  // scores (registers) + running max
  double sv[8];
  double lmax = -1e300;
  int nj = 0;
  const f32x4* kb = (const f32x4*)&k[(size_t)blockIdx.y*qs];
  int j = t;
  for (; j + 256 <= i; j += 512, nj += 2){
    const f32x4* kr0 = kb + (size_t)j*16;
    const f32x4* kr1 = kb + (size_t)(j+256)*16;
    double a0=0.0, a1=0.0, a2=0.0, a3=0.0;
    double b0=0.0, b1=0.0, b2=0.0, b3=0.0;
    #pragma unroll
    for (int d4=0; d4<16; d4++){
      const double s0 = sq[d4*4+0], s1 = sq[d4*4+1];
      const double s2 = sq[d4*4+2], s3 = sq[d4*4+3];
      f32x4 kv0 = kr0[d4];
      f32x4 kv1 = kr1[d4];
      a0 = fma((double)kv0[0], s0, a0);
      a1 = fma((double)kv0[1], s1, a1);
      a2 = fma((double)kv0[2], s2, a2);
      a3 = fma((double)kv0[3], s3, a3);
      b0 = fma((double)kv1[0], s0, b0);
      b1 = fma((double)kv1[1], s1, b1);
      b2 = fma((double)kv1[2], s2, b2);
      b3 = fma((double)kv1[3], s3, b3);
    }
    double e0 = ((u < 1e5) ? u : 1e5) * 0.125;
    const double sA = ((a0+a1)+(a2+a3)) * e0;
    sv[nj] = sA;
    lmax = (lmax > sA) ? lmax : sA;
    u *= step;
    double e1 = ((u < 1e5) ? u : 1e5) * 0.125;
    const double sB = ((b0+b1)+(b2+b3)) * e1;
    sv[nj+1] = sB;
    lmax = (lmax > sB) ? lmax : sB;
    u *= step;
  }
  for (; j <= i; j += 256, nj++){
    const f32x4* kr = kb + (size_t)j*16;
    double a0=0.0, a1=0.0, a2=0.0, a3=0.0;
    #pragma unroll
    for (int d4=0; d4<16; d4++){
      f32x4 kv = kr[d4];
      a0 = fma((double)kv[0], sq[d4*4+0], a0);
      a1 = fma((double)kv[1], sq[d4*4+1], a1);
      a2 = fma((double)kv[2], sq[d4*4+2], a2);
      a3 = fma((double)kv[3], sq[d4*4+3], a3);
    }
    double e = ((u < 1e5) ? u : 1e5) * 0.125;
    const double s = ((a0+a1)+(a2+a3)) * e;
    sv[nj] = s;
    lmax = (lmax > s) ? lmax : s;
    u *= step;
  }
  #pragma unroll
  for (int m2=1;m2<64;m2<<=1){ double o2 = __shfl_xor(lmax,m2,64); lmax = (lmax>o2)?lmax:o2; }
  if (L==0) red[wid] = lmax;
  __syncthreads();
  double m = red[0];
  m = (m>red[1])?m:red[1]; m = (m>red[2])?m:red[2]; m = (m>red[3])?m:red[3];
  __syncthreads();

  // exp (f32) + sum
  float ev[8];
  double lsum = 0.0;
  nj = 0;
  for (j = t; j <= i; j += 256, nj++){
    float e = expf((float)(sv[nj] - m));
    ev[nj] = e;
    lsum += (double)e;
  }
  #pragma unroll
  for (int m2=1;m2<64;m2<<=1) lsum += __shfl_xor(lsum,m2,64);
  if (L==0) red[wid] = lsum;
  __syncthreads();
  const float inv = (float)(1.0 / (red[0]+red[1]+red[2]+red[3]));
  nj = 0;
  for (j = t; j <= i; j += 256, nj++) p[j] = ev[nj]*inv;
  __syncthreads();

  if (wa){
    float* rb = &att[((size_t)bh*SS + i)*SS];
    for (int jj = t; jj < SS; jj += 256)
      rb[jj] = (jj <= i) ? p[jj] : 0.f;
  }
  if (wc){
    const int gg = t>>6, d = t&63;
    const float* vr = &vb[(size_t)bh*SS*DK + d];
    float a0=0.f, a1=0.f, a2=0.f, a3=0.f;
    int jj = gg;
    for (; jj+12 <= i; jj += 16){
      a0 = fmaf(p[jj   ], vr[(size_t)(jj   )*DK], a0);
      a1 = fmaf(p[jj+ 4], vr[(size_t)(jj+ 4)*DK], a1);
      a2 = fmaf(p[jj+ 8], vr[(size_t)(jj+ 8)*DK], a2);
      a3 = fmaf(p[jj+12], vr[(size_t)(jj+12)*DK], a3);
    }
    for (; jj <= i; jj += 4) a0 = fmaf(p[jj], vr[(size_t)jj*DK], a0);
    cpart[gg][d] = (a0+a1)+(a2+a3);
    __syncthreads();
    if (t < 64){
      const float cc = cpart[0][t]+cpart[1][t]+cpart[2][t]+cpart[3][t];
      ctx[((size_t)(b*SS + i)*NH + h)*DK + t] = cc;
    }
  }
}

// -------------------------------------------------- corner: bh63 rows 0..127
__global__ __launch_bounds__(256) void attn_corner(
  const float* __restrict__ src, const float* __restrict__ gammas,
  float* __restrict__ att)
{
  __shared__ float lq[128*64];
  __shared__ float lk[128*64];
  const int t = threadIdx.x;
  for (int idx = t; idx < 128*64; idx += 256){
    lq[idx] = src[idx];
    lk[idx] = src[QKS + idx];
  }
  __syncthreads();
  const double sp = softplus64(gammas[15]);
  const int w = t>>6, L = t&63;
  for (int i = w; i < 128; i += 4){
    double s0 = -1e300, s1 = -1e300;
    if (L <= i){
      double a = 0.0;
      for (int d=0; d<64; d++) a = fma((double)lq[i*64+d], (double)lk[L*64+d], a);
      double eff = exp((double)(i-L)*(1.0/21.0)*sp); eff = (eff<1e5)?eff:1e5;
      s0 = a * 0.125 * eff;
    }
    if (64+L <= i){
      double a = 0.0;
      for (int d=0; d<64; d++) a = fma((double)lq[i*64+d], (double)lk[(64+L)*64+d], a);
      double eff = exp((double)(i-64-L)*(1.0/21.0)*sp); eff = (eff<1e5)?eff:1e5;
      s1 = a * 0.125 * eff;
    }
    double mx = (s0>s1)?s0:s1;
    #pragma unroll
    for (int m2=1;m2<64;m2<<=1){ double o2 = __shfl_xor(mx,m2,64); mx = (mx>o2)?mx:o2; }
    double e0 = (L<=i)    ? exp(s0-mx) : 0.0;
    double e1 = (64+L<=i) ? exp(s1-mx) : 0.0;
    double su = e0+e1;
    #pragma unroll
    for (int m2=1;m2<64;m2<<=1) su += __shfl_xor(su,m2,64);
    const double inv = 1.0/su;
    const float p0 = (float)(e0*inv), p1 = (float)(e1*inv);
    float* rb = &att[((size_t)63*SS + i)*SS];
    #pragma unroll
    for (int tt=0; tt<32; tt++)
      rb[tt*64+L] = (tt==0) ? p0 : (tt==1) ? p1 : 0.f;
  }
}

// -------------------------------------------------- layernorm (f32)
__global__ __launch_bounds__(256) void lnorm(
  const float* __restrict__ a, const float* __restrict__ b,
  const float* __restrict__ sc, const float* __restrict__ bi,
  float* __restrict__ out)
{
  __shared__ float red[4];
  const int row = blockIdx.x, tid = threadIdx.x, wid = tid>>6;
  const size_t rb = (size_t)row*D_MODEL;
  float x[4];
  #pragma unroll
  for (int i=0;i<4;i++){
    const int c = tid + i*256;
    x[i] = a[rb+c] + b[rb+c];
  }
  float s = x[0]+x[1]+x[2]+x[3];
  for (int m2=1;m2<64;m2<<=1) s += __shfl_xor(s,m2,64);
  if ((tid&63)==0) red[wid] = s;
  __syncthreads();
  const float mu = (red[0]+red[1]+red[2]+red[3]) * (1.0f/1024.0f);
  __syncthreads();
  float ss2 = 0.f;
  #pragma unroll
  for (int i=0;i<4;i++){ float d = x[i]-mu; ss2 += d*d; }
  for (int m2=1;m2<64;m2<<=1) ss2 += __shfl_xor(ss2,m2,64);
  if ((tid&63)==0) red[wid] = ss2;
  __syncthreads();
  const float var = (red[0]+red[1]+red[2]+red[3]) * (1.0f/1024.0f);
  const float inv = rsqrtf(var + 1e-5f);
  #pragma unroll
  for (int i=0;i<4;i++){
    const int c = tid + i*256;
    out[rb+c] = (x[i]-mu)*inv*sc[c] + bi[c];
  }
}

// ------------------------------------------------------------------ launch
// Scratch map (inside att output, 64 blocks of 16 MiB):
//   blocks 0-2   : bf16 weight splits (46 MiB, live until last FFN gemm)
//   blocks 3-4   : vbp  -> then aof   (sequential reuse)
//   blocks 5-6   : ctxb -> then x1f   (sequential reuse)
//   blocks 7-8   : hbuf chunk (FFN M-chunked x4: 32 MiB instead of 128)
//   blocks 9-10  : fbuf
//   blocks 60-63 : QF / KF
// => fused attention writes att for bh 11..59 in pass A; bh 0..10 deferred,
//    bh 60..63 tail staged via D1/D2 copies.
extern "C" void kernel_launch(void* const* d_in, const int* in_sizes, int n_in,
                              void* d_out, int out_size, void* d_ws, size_t ws_size,
                              hipStream_t stream)
{
  const float* query  = (const float*)d_in[0];
  const float* key    = (const float*)d_in[1];
  const float* values = (const float*)d_in[2];
  const float* Wk   = (const float*)d_in[3];
  const float* bk   = (const float*)d_in[4];
  const float* Wv   = (const float*)d_in[5];
  const float* bv   = (const float*)d_in[6];
  const float* Wout = (const float*)d_in[7];
  const float* bout = (const float*)d_in[8];
  const float* gammas = (const float*)d_in[9];
  const float* ln1s = (const float*)d_in[10];
  const float* ln1b = (const float*)d_in[11];
  const float* W1   = (const float*)d_in[12];
  const float* b1   = (const float*)d_in[13];
  const float* W2   = (const float*)d_in[14];
  const float* b2   = (const float*)d_in[15];
  const float* ln2s = (const float*)d_in[16];
  const float* ln2b = (const float*)d_in[17];

  float* outx = (float*)d_out;
  float* att  = outx + (size_t)ROWS*D_MODEL;

  char* sc = (char*)att;
  u16* WkTh  = (u16*)(sc +  0*MiB);
  u16* WkTm  = (u16*)(sc +  2*MiB);
  u16* WkTl  = (u16*)(sc +  4*MiB);
  u16* WvTh  = (u16*)(sc +  6*MiB);
  u16* WvTl  = (u16*)(sc +  8*MiB);
  u16* WoTh  = (u16*)(sc + 10*MiB);
  u16* WoTl  = (u16*)(sc + 12*MiB);
  u16* W1Th  = (u16*)(sc + 14*MiB);
  u16* W1Tl  = (u16*)(sc + 22*MiB);
  u16* W2Th  = (u16*)(sc + 30*MiB);
  u16* W2Tl  = (u16*)(sc + 38*MiB);
  float* vbp  = (float*)(sc +  48*MiB);   // blocks 3-4
  float* ctxb = (float*)(sc +  80*MiB);   // blocks 5-6
  float* aof  = (float*)(sc +  48*MiB);   // reuse 3-4 after vbp dead
  float* x1f  = (float*)(sc +  80*MiB);   // reuse 5-6 after ctxb dead
  float* hbuf = (float*)(sc + 112*MiB);   // blocks 7-8 (32 MiB chunk)
  float* fbuf = (float*)(sc + 144*MiB);   // blocks 9-10
  float* QF = att + 60*BHSZ;
  float* KF = att + 62*BHSZ;
  float* D1 = att + 63*BHSZ + 2*(MiB/4)*4;
  float* D2 = att + 63*BHSZ;

  dim3 th(256);
  twc<<<dim3(32,32),  th, 0, stream>>>(Wk,   WkTh, WkTm, WkTl, 1024, 1024);
  twc<<<dim3(32,32),  th, 0, stream>>>(Wv,   WvTh, WvTl, nullptr, 1024, 1024);
  twc<<<dim3(32,32),  th, 0, stream>>>(Wout, WoTh, WoTl, nullptr, 1024, 1024);
  twc<<<dim3(128,32), th, 0, stream>>>(W1,   W1Th, W1Tl, nullptr, 1024, 4096);
  twc<<<dim3(32,128), th, 0, stream>>>(W2,   W2Th, W2Tl, nullptr, 4096, 1024);
  gemm3<<<dim3(8,64), th, 0, stream>>>(query, WkTh, WkTm, WkTl, bk, ROWS, 1024, 1024, QF);
  gemm3<<<dim3(8,64), th, 0, stream>>>(key,   WkTh, WkTm, WkTl, bk, ROWS, 1024, 1024, KF);
  gemm2<<<dim3(8,64), th, 0, stream>>>(values, WvTh, WvTl, bv, ROWS, 1024, 1024, 2, vbp);
  // fused attention: ctx for all 64 bh, att for bh 11..59
  attn_row<<<dim3(SS,64), th, 0, stream>>>(QF, KF, (long long)QKS, 0, 0,
                                           vbp, gammas, att, ctxb, 11, 60, 1);
  gemm2<<<dim3(8,64),  th, 0, stream>>>(ctxb, WoTh, WoTl, bout, ROWS, 1024, 1024, 0, aof);
  lnorm<<<dim3(ROWS), th, 0, stream>>>(query, aof, ln1s, ln1b, x1f);
  // FFN, M-chunked x4 so hbuf is 32 MiB (frees att blocks 11..21 for the fuse)
  for (int c = 0; c < 4; ++c){
    gemm2<<<dim3(32,16), th, 0, stream>>>(x1f + (size_t)c*2048*1024, W1Th, W1Tl, b1,
                                          2048, 4096, 1024, 1, hbuf);
    gemm2<<<dim3(8,16),  th, 0, stream>>>(hbuf, W2Th, W2Tl, b2,
                                          2048, 1024, 4096, 0, fbuf + (size_t)c*2048*1024);
  }
  lnorm<<<dim3(ROWS), th, 0, stream>>>(x1f, fbuf, ln2s, ln2b, outx);
  // deferred att for bh 0..10 (scratch regions now dead)
  attn_row<<<dim3(SS,11), th, 0, stream>>>(QF, KF, (long long)QKS, 0, 0,
                                           vbp, gammas, att, ctxb, 0, 64, 0);
  // bh 60..63 tail (unchanged): stage q/k slices out of the regions being written
  copyf<<<dim3(512), th, 0, stream>>>(D1,            QF + 60*QKS, 4*(long long)QKS);
  copyf<<<dim3(512), th, 0, stream>>>(D1 + 4*QKS,    KF + 60*QKS, 4*(long long)QKS);
  attn_row<<<dim3(SS,3), th, 0, stream>>>(D1, D1 + 4*QKS, (long long)QKS, 60, 0,
                                          vbp, gammas, att, ctxb, 0, 64, 0);
  attn_row<<<dim3(512,1), th, 0, stream>>>(D1 + 3*QKS, D1 + 7*QKS, 0ll, 63, 1536,
                                           vbp, gammas, att, ctxb, 0, 64, 0);
  copyf<<<dim3(128), th, 0, stream>>>(D2,        D1 + 3*QKS, (long long)QKS);
  copyf<<<dim3(128), th, 0, stream>>>(D2 + QKS,  D1 + 7*QKS, (long long)QKS);
  attn_row<<<dim3(1408,1), th, 0, stream>>>(D2, D2 + QKS, 0ll, 63, 128,
                                            vbp, gammas, att, ctxb, 0, 64, 0);
  attn_corner<<<dim3(1), th, 0, stream>>>(D2, gammas, att);
}

// Round 4
// 6137.854 us; speedup vs baseline: 1.6754x; 1.6754x over previous
//
#include <hip/hip_runtime.h>
#include <math.h>

typedef unsigned short u16;
typedef float f32x4 __attribute__((ext_vector_type(4)));
typedef short s16x8 __attribute__((ext_vector_type(8)));

#define D_MODEL 1024
#define NH 16
#define DK 64
#define DFF 4096
#define BB 4
#define SS 2048
#define ROWS (BB*SS)   // 8192
#define MiB 1048576ull
#define BHSZ 4194304ull   // floats per att[bh] block (2048*2048)
#define QKS  131072ull    // floats per bh slice of q/k (2048*64)

static __device__ __forceinline__ float bf2f(u16 v){
  union{unsigned u; float f;} x; x.u = ((unsigned)v)<<16; return x.f;
}
static __device__ __forceinline__ u16 f2bf(float f){
  union{float f; unsigned u;} x; x.f=f;
  unsigned r = x.u + 0x7fffu + ((x.u>>16)&1u);
  return (u16)(r>>16);
}
static __device__ __forceinline__ double softplus64(float gf){
  double g = (double)gf;
  return (g > 0.0) ? g + log1p(exp(-g)) : log1p(exp(g));
}

// -------------------------------------------------- transpose + f32->bf16 split
__global__ __launch_bounds__(256) void twc(const float* __restrict__ in,
    u16* __restrict__ oh, u16* __restrict__ om, u16* __restrict__ ol, int R, int C){
  __shared__ float t[32][33];
  int c0 = blockIdx.x*32, r0 = blockIdx.y*32;
  int tx = threadIdx.x & 31, ty = threadIdx.x >> 5;
  for (int i=ty; i<32; i+=8) t[i][tx] = in[(size_t)(r0+i)*C + c0 + tx];
  __syncthreads();
  for (int i=ty; i<32; i+=8){
    float x = t[tx][i];
    u16 h = f2bf(x);
    size_t o = (size_t)(c0+i)*R + r0 + tx;
    oh[o] = h;
    if (om){
      float r1 = x - bf2f(h);
      u16 m = f2bf(r1);
      om[o] = m;
      if (ol){ float r2 = r1 - bf2f(m); ol[o] = f2bf(r2); }
    }
  }
}

// -------------------------------------------------- f32 copy
__global__ __launch_bounds__(256) void copyf(float* __restrict__ dst,
                                             const float* __restrict__ src, long long n){
  long long i = (long long)blockIdx.x*256 + threadIdx.x;
  long long stride = (long long)gridDim.x*256;
  for (; i < n; i += stride) dst[i] = src[i];
}

// -------------------------------------------------- triple-split GEMM (Q/K proj)
// kt=0: o[bh][s][d] layout; kt=1: o[bh][d][s] (K transposed for attn coalescing)
__global__ __launch_bounds__(256) void gemm3(
    const float* __restrict__ A, const u16* __restrict__ Bh,
    const u16* __restrict__ Bm, const u16* __restrict__ Bl,
    const float* __restrict__ bias, int M, int N, int K, int kt, float* __restrict__ o)
{
  __shared__ u16 lAh[128*32], lAm[128*32], lAl[128*32];
  __shared__ u16 lBh[128*32], lBm[128*32], lBl[128*32];
  const int tid = threadIdx.x, wid = tid>>6, L = tid&63;
  const int m0 = blockIdx.y*128, n0 = blockIdx.x*128;
  const int wm = (wid>>1)*64, wn = (wid&1)*64;
  f32x4 acc[4][4] = {};
  const int srow = wid*32 + (L>>2);
  const int scol = (L&3)*8;
  for (int ktile=0; ktile<K; ktile+=32){
    s16x8 ah[2], am[2], al[2], vbh[2], vbm[2], vbl[2];
    #pragma unroll
    for (int rr=0; rr<2; rr++){
      const float* ap = &A[(size_t)(m0 + srow + rr*16)*K + ktile + scol];
      #pragma unroll
      for (int e=0;e<8;e++){
        float x = ap[e];
        u16 hh = f2bf(x); float r1 = x - bf2f(hh);
        u16 mm = f2bf(r1); float r2 = r1 - bf2f(mm);
        ah[rr][e] = (short)hh; am[rr][e] = (short)mm; al[rr][e] = (short)f2bf(r2);
      }
      const size_t bo = (size_t)(n0 + srow + rr*16)*K + ktile + scol;
      vbh[rr] = *(const s16x8*)&Bh[bo];
      vbm[rr] = *(const s16x8*)&Bm[bo];
      vbl[rr] = *(const s16x8*)&Bl[bo];
    }
    __syncthreads();
    #pragma unroll
    for (int rr=0; rr<2; rr++){
      const int ro = (srow + rr*16)*32 + scol;
      *(s16x8*)&lAh[ro] = ah[rr]; *(s16x8*)&lAm[ro] = am[rr]; *(s16x8*)&lAl[ro] = al[rr];
      *(s16x8*)&lBh[ro] = vbh[rr]; *(s16x8*)&lBm[ro] = vbm[rr]; *(s16x8*)&lBl[ro] = vbl[rr];
    }
    __syncthreads();
    const int lro = (L&15)*32 + (L>>4)*8;
    s16x8 afh[4], afm[4], afl[4], bfh[4], bfm[4], bfl[4];
    #pragma unroll
    for (int t=0;t<4;t++){
      afh[t] = *(const s16x8*)&lAh[(wm + t*16)*32 + lro];
      afm[t] = *(const s16x8*)&lAm[(wm + t*16)*32 + lro];
      afl[t] = *(const s16x8*)&lAl[(wm + t*16)*32 + lro];
      bfh[t] = *(const s16x8*)&lBh[(wn + t*16)*32 + lro];
      bfm[t] = *(const s16x8*)&lBm[(wn + t*16)*32 + lro];
      bfl[t] = *(const s16x8*)&lBl[(wn + t*16)*32 + lro];
    }
    #pragma unroll
    for (int mt=0;mt<4;mt++)
      #pragma unroll
      for (int nt=0;nt<4;nt++){
        f32x4 a2 = acc[mt][nt];
        a2 = __builtin_amdgcn_mfma_f32_16x16x32_bf16(afl[mt], bfh[nt], a2, 0,0,0);
        a2 = __builtin_amdgcn_mfma_f32_16x16x32_bf16(afm[mt], bfm[nt], a2, 0,0,0);
        a2 = __builtin_amdgcn_mfma_f32_16x16x32_bf16(afh[mt], bfl[nt], a2, 0,0,0);
        a2 = __builtin_amdgcn_mfma_f32_16x16x32_bf16(afm[mt], bfh[nt], a2, 0,0,0);
        a2 = __builtin_amdgcn_mfma_f32_16x16x32_bf16(afh[mt], bfm[nt], a2, 0,0,0);
        a2 = __builtin_amdgcn_mfma_f32_16x16x32_bf16(afh[mt], bfh[nt], a2, 0,0,0);
        acc[mt][nt] = a2;
      }
  }
  #pragma unroll
  for (int mt=0;mt<4;mt++)
    #pragma unroll
    for (int nt=0;nt<4;nt++){
      const int gn = n0 + wn + nt*16 + (L&15);
      const float bvv = bias[gn];
      const int gmb = m0 + wm + mt*16 + (L>>4)*4;
      const int h = gn>>6, d = gn&63;
      #pragma unroll
      for (int r=0;r<4;r++){
        const int gm = gmb + r, b = gm>>11, s = gm&2047;
        const float v = acc[mt][nt][r] + bvv;
        if (kt) o[((size_t)(b*NH+h)*DK + d)*SS + s] = v;
        else    o[((size_t)(b*NH+h)*SS + s)*DK + d] = v;
      }
    }
}

// -------------------------------------------------- pair-split GEMM (~f32 quality)
__global__ __launch_bounds__(256) void gemm2(
    const float* __restrict__ A, const u16* __restrict__ Bh, const u16* __restrict__ Bl,
    const float* __restrict__ bias, int M, int N, int K, int mode, float* __restrict__ o)
{
  __shared__ u16 lAh[128*32], lAl[128*32], lBh[128*32], lBl[128*32];
  const int tid = threadIdx.x, wid = tid>>6, L = tid&63;
  const int m0 = blockIdx.y*128, n0 = blockIdx.x*128;
  const int wm = (wid>>1)*64, wn = (wid&1)*64;
  f32x4 acc[4][4] = {};
  const int srow = wid*32 + (L>>2);
  const int scol = (L&3)*8;
  for (int kt=0; kt<K; kt+=32){
    s16x8 ah[2], al[2], vbh[2], vbl[2];
    #pragma unroll
    for (int rr=0; rr<2; rr++){
      const float* ap = &A[(size_t)(m0 + srow + rr*16)*K + kt + scol];
      #pragma unroll
      for (int e=0;e<8;e++){
        float x = ap[e];
        u16 hh = f2bf(x);
        ah[rr][e] = (short)hh;
        al[rr][e] = (short)f2bf(x - bf2f(hh));
      }
      const size_t bo = (size_t)(n0 + srow + rr*16)*K + kt + scol;
      vbh[rr] = *(const s16x8*)&Bh[bo];
      vbl[rr] = *(const s16x8*)&Bl[bo];
    }
    __syncthreads();
    #pragma unroll
    for (int rr=0; rr<2; rr++){
      const int ro = (srow + rr*16)*32 + scol;
      *(s16x8*)&lAh[ro] = ah[rr]; *(s16x8*)&lAl[ro] = al[rr];
      *(s16x8*)&lBh[ro] = vbh[rr]; *(s16x8*)&lBl[ro] = vbl[rr];
    }
    __syncthreads();
    const int lro = (L&15)*32 + (L>>4)*8;
    s16x8 afh[4], afl[4], bfh[4], bfl[4];
    #pragma unroll
    for (int t=0;t<4;t++){
      afh[t] = *(const s16x8*)&lAh[(wm + t*16)*32 + lro];
      afl[t] = *(const s16x8*)&lAl[(wm + t*16)*32 + lro];
      bfh[t] = *(const s16x8*)&lBh[(wn + t*16)*32 + lro];
      bfl[t] = *(const s16x8*)&lBl[(wn + t*16)*32 + lro];
    }
    #pragma unroll
    for (int mt=0;mt<4;mt++)
      #pragma unroll
      for (int nt=0;nt<4;nt++){
        f32x4 a2 = acc[mt][nt];
        a2 = __builtin_amdgcn_mfma_f32_16x16x32_bf16(afl[mt], bfh[nt], a2, 0,0,0);
        a2 = __builtin_amdgcn_mfma_f32_16x16x32_bf16(afh[mt], bfl[nt], a2, 0,0,0);
        a2 = __builtin_amdgcn_mfma_f32_16x16x32_bf16(afh[mt], bfh[nt], a2, 0,0,0);
        acc[mt][nt] = a2;
      }
  }
  #pragma unroll
  for (int mt=0;mt<4;mt++)
    #pragma unroll
    for (int nt=0;nt<4;nt++){
      const int gn = n0 + wn + nt*16 + (L&15);
      const float bvv = bias[gn];
      const int gmb = m0 + wm + mt*16 + (L>>4)*4;
      #pragma unroll
      for (int r=0;r<4;r++){
        const int gm = gmb + r;
        float v = acc[mt][nt][r] + bvv;
        if (mode==0)      o[(size_t)gm*N + gn] = v;
        else if (mode==1) o[(size_t)gm*N + gn] = fmaxf(v, 0.f);
        else {
          const int b = gm>>11, s = gm&2047, h = gn>>6, d = gn&63;
          o[((size_t)(b*NH+h)*SS + s)*DK + d] = v;
        }
      }
    }
}

// -------------------------------------------------- attention row kernel (v5)
// K is TRANSPOSED: KT[bh][d][s]. Thread t handles j = tile*1024 + 4t + e
// (4 consecutive j) so each wave's load KT[d][j0..j0+255] is 16B/lane
// coalesced (8 cache lines/instr instead of 64). f64 dots; eff via exact
// per-thread recurrence: u=exp(c*(i-4t)), *exp(-c) per e, *exp(-1024c)/tile.
__global__ __launch_bounds__(256) void attn_row(
  const float* __restrict__ q, const float* __restrict__ k, long long qs,
  int bh0, int row0,
  const float* __restrict__ vb, const float* __restrict__ gammas,
  float* __restrict__ att, float* __restrict__ ctx,
  int aw_lo, int aw_hi, int wc)
{
  __shared__ double sq[64];
  __shared__ float  p[SS];        // normalized probs (cross-thread)
  __shared__ double red[4];
  __shared__ float  cpart[4][64];
  const int i = row0 + blockIdx.x;
  const int bh = bh0 + blockIdx.y, h = bh&15, b = bh>>4;
  const int wa = (bh >= aw_lo) && (bh < aw_hi);
  const int t = threadIdx.x, wid = t>>6, L = t&63;
  const double c = softplus64(gammas[h]) * (1.0/21.0);

  if (t < 64) sq[t] = (double)q[(size_t)blockIdx.y*qs + (size_t)i*DK + t];
  const double ce1   = exp(-c);
  const double tstep = exp(-1024.0 * c);
  double u = exp(c * (double)(i - 4*t));   // eff state at (tile=0, e=0)
  __syncthreads();

  const float* kb = k + (size_t)blockIdx.y*qs;   // KT base [d][s]
  double sv[8];
  double lmax = -1e300;
  #pragma unroll
  for (int tile=0; tile<2; tile++){
    const int j0 = tile*1024 + 4*t;
    if (j0 <= i){
      const float* kcol = kb + j0;
      double a0=0.0, a1=0.0, a2=0.0, a3=0.0;
      #pragma unroll 8
      for (int d=0; d<64; d++){
        f32x4 kv = *(const f32x4*)(kcol + (size_t)d*SS);
        const double qd = sq[d];
        a0 = fma((double)kv[0], qd, a0);
        a1 = fma((double)kv[1], qd, a1);
        a2 = fma((double)kv[2], qd, a2);
        a3 = fma((double)kv[3], qd, a3);
      }
      double uu = u;
      double ef = ((uu < 1e5) ? uu : 1e5) * 0.125;
      double s0 = a0 * ef;                       // j0 <= i guaranteed here
      sv[tile*4+0] = s0; lmax = (lmax > s0) ? lmax : s0;
      uu *= ce1;
      ef = ((uu < 1e5) ? uu : 1e5) * 0.125;
      double s1 = (j0+1 <= i) ? a1 * ef : -1e300;
      sv[tile*4+1] = s1; lmax = (lmax > s1) ? lmax : s1;
      uu *= ce1;
      ef = ((uu < 1e5) ? uu : 1e5) * 0.125;
      double s2 = (j0+2 <= i) ? a2 * ef : -1e300;
      sv[tile*4+2] = s2; lmax = (lmax > s2) ? lmax : s2;
      uu *= ce1;
      ef = ((uu < 1e5) ? uu : 1e5) * 0.125;
      double s3 = (j0+3 <= i) ? a3 * ef : -1e300;
      sv[tile*4+3] = s3; lmax = (lmax > s3) ? lmax : s3;
    }
    u *= tstep;
  }
  #pragma unroll
  for (int m2=1;m2<64;m2<<=1){ double o2 = __shfl_xor(lmax,m2,64); lmax = (lmax>o2)?lmax:o2; }
  if (L==0) red[wid] = lmax;
  __syncthreads();
  double m = red[0];
  m = (m>red[1])?m:red[1]; m = (m>red[2])?m:red[2]; m = (m>red[3])?m:red[3];
  __syncthreads();

  // exp (f32) + sum
  float ev[8];
  double lsum = 0.0;
  #pragma unroll
  for (int tile=0; tile<2; tile++){
    const int j0 = tile*1024 + 4*t;
    if (j0 <= i){
      #pragma unroll
      for (int e=0;e<4;e++){
        float ex = expf((float)(sv[tile*4+e] - m));
        ev[tile*4+e] = ex;
        lsum += (double)ex;
      }
    }
  }
  #pragma unroll
  for (int m2=1;m2<64;m2<<=1) lsum += __shfl_xor(lsum,m2,64);
  if (L==0) red[wid] = lsum;
  __syncthreads();
  const float inv = (float)(1.0 / (red[0]+red[1]+red[2]+red[3]));
  #pragma unroll
  for (int tile=0; tile<2; tile++){
    const int j0 = tile*1024 + 4*t;
    if (j0 <= i){
      f32x4 pv;
      pv[0] = ev[tile*4+0]*inv; pv[1] = ev[tile*4+1]*inv;
      pv[2] = ev[tile*4+2]*inv; pv[3] = ev[tile*4+3]*inv;
      *(f32x4*)&p[j0] = pv;
    }
  }
  __syncthreads();

  if (wa){
    float* rb = &att[((size_t)bh*SS + i)*SS];
    for (int jj = t; jj < SS; jj += 256)
      rb[jj] = (jj <= i) ? p[jj] : 0.f;
  }
  if (wc){
    const int gg = t>>6, d = t&63;
    const float* vr = &vb[(size_t)bh*SS*DK + d];
    float a0=0.f, a1=0.f, a2=0.f, a3=0.f;
    int jj = gg;
    for (; jj+12 <= i; jj += 16){
      a0 = fmaf(p[jj   ], vr[(size_t)(jj   )*DK], a0);
      a1 = fmaf(p[jj+ 4], vr[(size_t)(jj+ 4)*DK], a1);
      a2 = fmaf(p[jj+ 8], vr[(size_t)(jj+ 8)*DK], a2);
      a3 = fmaf(p[jj+12], vr[(size_t)(jj+12)*DK], a3);
    }
    for (; jj <= i; jj += 4) a0 = fmaf(p[jj], vr[(size_t)jj*DK], a0);
    cpart[gg][d] = (a0+a1)+(a2+a3);
    __syncthreads();
    if (t < 64){
      const float cc = cpart[0][t]+cpart[1][t]+cpart[2][t]+cpart[3][t];
      ctx[((size_t)(b*SS + i)*NH + h)*DK + t] = cc;
    }
  }
}

// -------------------------------------------------- corner: bh63 rows 0..127
// src: [Q slice [s][d] | KT slice [d][s]]
__global__ __launch_bounds__(256) void attn_corner(
  const float* __restrict__ src, const float* __restrict__ gammas,
  float* __restrict__ att)
{
  __shared__ float lq[128*64];
  __shared__ float lk[128*64];
  const int t = threadIdx.x;
  for (int idx = t; idx < 128*64; idx += 256)
    lq[idx] = src[idx];                              // Q rows 0..127, [s][d]
  for (int idx = t; idx < 64*128; idx += 256){
    const int d = idx >> 7, s = idx & 127;           // KT[d][s] -> lk[s][d]
    lk[s*64 + d] = src[QKS + (size_t)d*SS + s];
  }
  __syncthreads();
  const double sp = softplus64(gammas[15]);
  const int w = t>>6, L = t&63;
  for (int i = w; i < 128; i += 4){
    double s0 = -1e300, s1 = -1e300;
    if (L <= i){
      double a = 0.0;
      for (int d=0; d<64; d++) a = fma((double)lq[i*64+d], (double)lk[L*64+d], a);
      double eff = exp((double)(i-L)*(1.0/21.0)*sp); eff = (eff<1e5)?eff:1e5;
      s0 = a * 0.125 * eff;
    }
    if (64+L <= i){
      double a = 0.0;
      for (int d=0; d<64; d++) a = fma((double)lq[i*64+d], (double)lk[(64+L)*64+d], a);
      double eff = exp((double)(i-64-L)*(1.0/21.0)*sp); eff = (eff<1e5)?eff:1e5;
      s1 = a * 0.125 * eff;
    }
    double mx = (s0>s1)?s0:s1;
    #pragma unroll
    for (int m2=1;m2<64;m2<<=1){ double o2 = __shfl_xor(mx,m2,64); mx = (mx>o2)?mx:o2; }
    double e0 = (L<=i)    ? exp(s0-mx) : 0.0;
    double e1 = (64+L<=i) ? exp(s1-mx) : 0.0;
    double su = e0+e1;
    #pragma unroll
    for (int m2=1;m2<64;m2<<=1) su += __shfl_xor(su,m2,64);
    const double inv = 1.0/su;
    const float p0 = (float)(e0*inv), p1 = (float)(e1*inv);
    float* rb = &att[((size_t)63*SS + i)*SS];
    #pragma unroll
    for (int tt=0; tt<32; tt++)
      rb[tt*64+L] = (tt==0) ? p0 : (tt==1) ? p1 : 0.f;
  }
}

// -------------------------------------------------- layernorm (f32)
__global__ __launch_bounds__(256) void lnorm(
  const float* __restrict__ a, const float* __restrict__ b,
  const float* __restrict__ sc, const float* __restrict__ bi,
  float* __restrict__ out)
{
  __shared__ float red[4];
  const int row = blockIdx.x, tid = threadIdx.x, wid = tid>>6;
  const size_t rb = (size_t)row*D_MODEL;
  float x[4];
  #pragma unroll
  for (int i=0;i<4;i++){
    const int c = tid + i*256;
    x[i] = a[rb+c] + b[rb+c];
  }
  float s = x[0]+x[1]+x[2]+x[3];
  for (int m2=1;m2<64;m2<<=1) s += __shfl_xor(s,m2,64);
  if ((tid&63)==0) red[wid] = s;
  __syncthreads();
  const float mu = (red[0]+red[1]+red[2]+red[3]) * (1.0f/1024.0f);
  __syncthreads();
  float ss2 = 0.f;
  #pragma unroll
  for (int i=0;i<4;i++){ float d = x[i]-mu; ss2 += d*d; }
  for (int m2=1;m2<64;m2<<=1) ss2 += __shfl_xor(ss2,m2,64);
  if ((tid&63)==0) red[wid] = ss2;
  __syncthreads();
  const float var = (red[0]+red[1]+red[2]+red[3]) * (1.0f/1024.0f);
  const float inv = rsqrtf(var + 1e-5f);
  #pragma unroll
  for (int i=0;i<4;i++){
    const int c = tid + i*256;
    out[rb+c] = (x[i]-mu)*inv*sc[c] + bi[c];
  }
}

// ------------------------------------------------------------------ launch
// Scratch map (inside att output, 64 blocks of 16 MiB):
//   blocks 0-2   : bf16 weight splits
//   blocks 3-4   : vbp  -> then aof
//   blocks 5-6   : ctxb -> then x1f
//   blocks 7-8   : hbuf chunk (FFN M-chunked x4)
//   blocks 9-10  : fbuf
//   blocks 60-61 : QF ([bh][s][d]);  blocks 62-63 : KF (KT: [bh][d][s])
// => fused attention writes att for bh 11..59 in pass A; bh 0..10 deferred,
//    bh 60..63 tail staged via D1/D2 copies (layout-agnostic slices).
extern "C" void kernel_launch(void* const* d_in, const int* in_sizes, int n_in,
                              void* d_out, int out_size, void* d_ws, size_t ws_size,
                              hipStream_t stream)
{
  const float* query  = (const float*)d_in[0];
  const float* key    = (const float*)d_in[1];
  const float* values = (const float*)d_in[2];
  const float* Wk   = (const float*)d_in[3];
  const float* bk   = (const float*)d_in[4];
  const float* Wv   = (const float*)d_in[5];
  const float* bv   = (const float*)d_in[6];
  const float* Wout = (const float*)d_in[7];
  const float* bout = (const float*)d_in[8];
  const float* gammas = (const float*)d_in[9];
  const float* ln1s = (const float*)d_in[10];
  const float* ln1b = (const float*)d_in[11];
  const float* W1   = (const float*)d_in[12];
  const float* b1   = (const float*)d_in[13];
  const float* W2   = (const float*)d_in[14];
  const float* b2   = (const float*)d_in[15];
  const float* ln2s = (const float*)d_in[16];
  const float* ln2b = (const float*)d_in[17];

  float* outx = (float*)d_out;
  float* att  = outx + (size_t)ROWS*D_MODEL;

  char* sc = (char*)att;
  u16* WkTh  = (u16*)(sc +  0*MiB);
  u16* WkTm  = (u16*)(sc +  2*MiB);
  u16* WkTl  = (u16*)(sc +  4*MiB);
  u16* WvTh  = (u16*)(sc +  6*MiB);
  u16* WvTl  = (u16*)(sc +  8*MiB);
  u16* WoTh  = (u16*)(sc + 10*MiB);
  u16* WoTl  = (u16*)(sc + 12*MiB);
  u16* W1Th  = (u16*)(sc + 14*MiB);
  u16* W1Tl  = (u16*)(sc + 22*MiB);
  u16* W2Th  = (u16*)(sc + 30*MiB);
  u16* W2Tl  = (u16*)(sc + 38*MiB);
  float* vbp  = (float*)(sc +  48*MiB);   // blocks 3-4
  float* ctxb = (float*)(sc +  80*MiB);   // blocks 5-6
  float* aof  = (float*)(sc +  48*MiB);   // reuse 3-4 after vbp dead
  float* x1f  = (float*)(sc +  80*MiB);   // reuse 5-6 after ctxb dead
  float* hbuf = (float*)(sc + 112*MiB);   // blocks 7-8 (32 MiB chunk)
  float* fbuf = (float*)(sc + 144*MiB);   // blocks 9-10
  float* QF = att + 60*BHSZ;
  float* KF = att + 62*BHSZ;
  float* D1 = att + 63*BHSZ + 2*(MiB/4)*4;
  float* D2 = att + 63*BHSZ;

  dim3 th(256);
  twc<<<dim3(32,32),  th, 0, stream>>>(Wk,   WkTh, WkTm, WkTl, 1024, 1024);
  twc<<<dim3(32,32),  th, 0, stream>>>(Wv,   WvTh, WvTl, nullptr, 1024, 1024);
  twc<<<dim3(32,32),  th, 0, stream>>>(Wout, WoTh, WoTl, nullptr, 1024, 1024);
  twc<<<dim3(128,32), th, 0, stream>>>(W1,   W1Th, W1Tl, nullptr, 1024, 4096);
  twc<<<dim3(32,128), th, 0, stream>>>(W2,   W2Th, W2Tl, nullptr, 4096, 1024);
  gemm3<<<dim3(8,64), th, 0, stream>>>(query, WkTh, WkTm, WkTl, bk, ROWS, 1024, 1024, 0, QF);
  gemm3<<<dim3(8,64), th, 0, stream>>>(key,   WkTh, WkTm, WkTl, bk, ROWS, 1024, 1024, 1, KF);
  gemm2<<<dim3(8,64), th, 0, stream>>>(values, WvTh, WvTl, bv, ROWS, 1024, 1024, 2, vbp);
  // fused attention: ctx for all 64 bh, att for bh 11..59
  attn_row<<<dim3(SS,64), th, 0, stream>>>(QF, KF, (long long)QKS, 0, 0,
                                           vbp, gammas, att, ctxb, 11, 60, 1);
  gemm2<<<dim3(8,64),  th, 0, stream>>>(ctxb, WoTh, WoTl, bout, ROWS, 1024, 1024, 0, aof);
  lnorm<<<dim3(ROWS), th, 0, stream>>>(query, aof, ln1s, ln1b, x1f);
  // FFN, M-chunked x4 so hbuf is 32 MiB
  for (int c = 0; c < 4; ++c){
    gemm2<<<dim3(32,16), th, 0, stream>>>(x1f + (size_t)c*2048*1024, W1Th, W1Tl, b1,
                                          2048, 4096, 1024, 1, hbuf);
    gemm2<<<dim3(8,16),  th, 0, stream>>>(hbuf, W2Th, W2Tl, b2,
                                          2048, 1024, 4096, 0, fbuf + (size_t)c*2048*1024);
  }
  lnorm<<<dim3(ROWS), th, 0, stream>>>(x1f, fbuf, ln2s, ln2b, outx);
  // deferred att for bh 0..10 (scratch regions now dead)
  attn_row<<<dim3(SS,11), th, 0, stream>>>(QF, KF, (long long)QKS, 0, 0,
                                           vbp, gammas, att, ctxb, 0, 64, 0);
  // bh 60..63 tail: stage q/k slices out of the regions being written
  copyf<<<dim3(512), th, 0, stream>>>(D1,            QF + 60*QKS, 4*(long long)QKS);
  copyf<<<dim3(512), th, 0, stream>>>(D1 + 4*QKS,    KF + 60*QKS, 4*(long long)QKS);
  attn_row<<<dim3(SS,3), th, 0, stream>>>(D1, D1 + 4*QKS, (long long)QKS, 60, 0,
                                          vbp, gammas, att, ctxb, 0, 64, 0);
  attn_row<<<dim3(512,1), th, 0, stream>>>(D1 + 3*QKS, D1 + 7*QKS, 0ll, 63, 1536,
                                           vbp, gammas, att, ctxb, 0, 64, 0);
  copyf<<<dim3(128), th, 0, stream>>>(D2,        D1 + 3*QKS, (long long)QKS);
  copyf<<<dim3(128), th, 0, stream>>>(D2 + QKS,  D1 + 7*QKS, (long long)QKS);
  attn_row<<<dim3(1408,1), th, 0, stream>>>(D2, D2 + QKS, 0ll, 63, 128,
                                            vbp, gammas, att, ctxb, 0, 64, 0);
  attn_corner<<<dim3(1), th, 0, stream>>>(D2, gammas, att);
}

// Round 6
// 5259.042 us; speedup vs baseline: 1.9553x; 1.1671x over previous
//
#include <hip/hip_runtime.h>
#include <math.h>

typedef unsigned short u16;
typedef float f32x4 __attribute__((ext_vector_type(4)));
typedef short s16x8 __attribute__((ext_vector_type(8)));

#define D_MODEL 1024
#define NH 16
#define DK 64
#define DFF 4096
#define BB 4
#define SS 2048
#define ROWS (BB*SS)   // 8192
#define MiB 1048576ull
#define BHSZ 4194304ull   // floats per att[bh] block (2048*2048)
#define QKS  131072ull    // floats per bh slice of q/k (2048*64)

static __device__ __forceinline__ float bf2f(u16 v){
  union{unsigned u; float f;} x; x.u = ((unsigned)v)<<16; return x.f;
}
static __device__ __forceinline__ u16 f2bf(float f){
  union{float f; unsigned u;} x; x.f=f;
  unsigned r = x.u + 0x7fffu + ((x.u>>16)&1u);
  return (u16)(r>>16);
}
static __device__ __forceinline__ double softplus64(float gf){
  double g = (double)gf;
  return (g > 0.0) ? g + log1p(exp(-g)) : log1p(exp(g));
}

// -------------------------------------------------- transpose + f32->bf16 split
__global__ __launch_bounds__(256) void twc(const float* __restrict__ in,
    u16* __restrict__ oh, u16* __restrict__ om, u16* __restrict__ ol, int R, int C){
  __shared__ float t[32][33];
  int c0 = blockIdx.x*32, r0 = blockIdx.y*32;
  int tx = threadIdx.x & 31, ty = threadIdx.x >> 5;
  for (int i=ty; i<32; i+=8) t[i][tx] = in[(size_t)(r0+i)*C + c0 + tx];
  __syncthreads();
  for (int i=ty; i<32; i+=8){
    float x = t[tx][i];
    u16 h = f2bf(x);
    size_t o = (size_t)(c0+i)*R + r0 + tx;
    oh[o] = h;
    if (om){
      float r1 = x - bf2f(h);
      u16 m = f2bf(r1);
      om[o] = m;
      if (ol){ float r2 = r1 - bf2f(m); ol[o] = f2bf(r2); }
    }
  }
}

// -------------------------------------------------- f32 copy
__global__ __launch_bounds__(256) void copyf(float* __restrict__ dst,
                                             const float* __restrict__ src, long long n){
  long long i = (long long)blockIdx.x*256 + threadIdx.x;
  long long stride = (long long)gridDim.x*256;
  for (; i < n; i += stride) dst[i] = src[i];
}

// -------------------------------------------------- triple-split GEMM (Q/K proj)
// kt=0: o[bh][s][d] layout; kt=1: o[bh][d][s] (K transposed for attn coalescing)
__global__ __launch_bounds__(256) void gemm3(
    const float* __restrict__ A, const u16* __restrict__ Bh,
    const u16* __restrict__ Bm, const u16* __restrict__ Bl,
    const float* __restrict__ bias, int M, int N, int K, int kt, float* __restrict__ o)
{
  __shared__ u16 lAh[128*32], lAm[128*32], lAl[128*32];
  __shared__ u16 lBh[128*32], lBm[128*32], lBl[128*32];
  const int tid = threadIdx.x, wid = tid>>6, L = tid&63;
  const int m0 = blockIdx.y*128, n0 = blockIdx.x*128;
  const int wm = (wid>>1)*64, wn = (wid&1)*64;
  f32x4 acc[4][4] = {};
  const int srow = wid*32 + (L>>2);
  const int scol = (L&3)*8;
  for (int ktile=0; ktile<K; ktile+=32){
    s16x8 ah[2], am[2], al[2], vbh[2], vbm[2], vbl[2];
    #pragma unroll
    for (int rr=0; rr<2; rr++){
      const float* ap = &A[(size_t)(m0 + srow + rr*16)*K + ktile + scol];
      #pragma unroll
      for (int e=0;e<8;e++){
        float x = ap[e];
        u16 hh = f2bf(x); float r1 = x - bf2f(hh);
        u16 mm = f2bf(r1); float r2 = r1 - bf2f(mm);
        ah[rr][e] = (short)hh; am[rr][e] = (short)mm; al[rr][e] = (short)f2bf(r2);
      }
      const size_t bo = (size_t)(n0 + srow + rr*16)*K + ktile + scol;
      vbh[rr] = *(const s16x8*)&Bh[bo];
      vbm[rr] = *(const s16x8*)&Bm[bo];
      vbl[rr] = *(const s16x8*)&Bl[bo];
    }
    __syncthreads();
    #pragma unroll
    for (int rr=0; rr<2; rr++){
      const int ro = (srow + rr*16)*32 + scol;
      *(s16x8*)&lAh[ro] = ah[rr]; *(s16x8*)&lAm[ro] = am[rr]; *(s16x8*)&lAl[ro] = al[rr];
      *(s16x8*)&lBh[ro] = vbh[rr]; *(s16x8*)&lBm[ro] = vbm[rr]; *(s16x8*)&lBl[ro] = vbl[rr];
    }
    __syncthreads();
    const int lro = (L&15)*32 + (L>>4)*8;
    s16x8 afh[4], afm[4], afl[4], bfh[4], bfm[4], bfl[4];
    #pragma unroll
    for (int t=0;t<4;t++){
      afh[t] = *(const s16x8*)&lAh[(wm + t*16)*32 + lro];
      afm[t] = *(const s16x8*)&lAm[(wm + t*16)*32 + lro];
      afl[t] = *(const s16x8*)&lAl[(wm + t*16)*32 + lro];
      bfh[t] = *(const s16x8*)&lBh[(wn + t*16)*32 + lro];
      bfm[t] = *(const s16x8*)&lBm[(wn + t*16)*32 + lro];
      bfl[t] = *(const s16x8*)&lBl[(wn + t*16)*32 + lro];
    }
    #pragma unroll
    for (int mt=0;mt<4;mt++)
      #pragma unroll
      for (int nt=0;nt<4;nt++){
        f32x4 a2 = acc[mt][nt];
        a2 = __builtin_amdgcn_mfma_f32_16x16x32_bf16(afl[mt], bfh[nt], a2, 0,0,0);
        a2 = __builtin_amdgcn_mfma_f32_16x16x32_bf16(afm[mt], bfm[nt], a2, 0,0,0);
        a2 = __builtin_amdgcn_mfma_f32_16x16x32_bf16(afh[mt], bfl[nt], a2, 0,0,0);
        a2 = __builtin_amdgcn_mfma_f32_16x16x32_bf16(afm[mt], bfh[nt], a2, 0,0,0);
        a2 = __builtin_amdgcn_mfma_f32_16x16x32_bf16(afh[mt], bfm[nt], a2, 0,0,0);
        a2 = __builtin_amdgcn_mfma_f32_16x16x32_bf16(afh[mt], bfh[nt], a2, 0,0,0);
        acc[mt][nt] = a2;
      }
  }
  #pragma unroll
  for (int mt=0;mt<4;mt++)
    #pragma unroll
    for (int nt=0;nt<4;nt++){
      const int gn = n0 + wn + nt*16 + (L&15);
      const float bvv = bias[gn];
      const int gmb = m0 + wm + mt*16 + (L>>4)*4;
      const int h = gn>>6, d = gn&63;
      #pragma unroll
      for (int r=0;r<4;r++){
        const int gm = gmb + r, b = gm>>11, s = gm&2047;
        const float v = acc[mt][nt][r] + bvv;
        if (kt) o[((size_t)(b*NH+h)*DK + d)*SS + s] = v;
        else    o[((size_t)(b*NH+h)*SS + s)*DK + d] = v;
      }
    }
}

// -------------------------------------------------- pair-split GEMM (~f32 quality)
__global__ __launch_bounds__(256) void gemm2(
    const float* __restrict__ A, const u16* __restrict__ Bh, const u16* __restrict__ Bl,
    const float* __restrict__ bias, int M, int N, int K, int mode, float* __restrict__ o)
{
  __shared__ u16 lAh[128*32], lAl[128*32], lBh[128*32], lBl[128*32];
  const int tid = threadIdx.x, wid = tid>>6, L = tid&63;
  const int m0 = blockIdx.y*128, n0 = blockIdx.x*128;
  const int wm = (wid>>1)*64, wn = (wid&1)*64;
  f32x4 acc[4][4] = {};
  const int srow = wid*32 + (L>>2);
  const int scol = (L&3)*8;
  for (int kt=0; kt<K; kt+=32){
    s16x8 ah[2], al[2], vbh[2], vbl[2];
    #pragma unroll
    for (int rr=0; rr<2; rr++){
      const float* ap = &A[(size_t)(m0 + srow + rr*16)*K + kt + scol];
      #pragma unroll
      for (int e=0;e<8;e++){
        float x = ap[e];
        u16 hh = f2bf(x);
        ah[rr][e] = (short)hh;
        al[rr][e] = (short)f2bf(x - bf2f(hh));
      }
      const size_t bo = (size_t)(n0 + srow + rr*16)*K + kt + scol;
      vbh[rr] = *(const s16x8*)&Bh[bo];
      vbl[rr] = *(const s16x8*)&Bl[bo];
    }
    __syncthreads();
    #pragma unroll
    for (int rr=0; rr<2; rr++){
      const int ro = (srow + rr*16)*32 + scol;
      *(s16x8*)&lAh[ro] = ah[rr]; *(s16x8*)&lAl[ro] = al[rr];
      *(s16x8*)&lBh[ro] = vbh[rr]; *(s16x8*)&lBl[ro] = vbl[rr];
    }
    __syncthreads();
    const int lro = (L&15)*32 + (L>>4)*8;
    s16x8 afh[4], afl[4], bfh[4], bfl[4];
    #pragma unroll
    for (int t=0;t<4;t++){
      afh[t] = *(const s16x8*)&lAh[(wm + t*16)*32 + lro];
      afl[t] = *(const s16x8*)&lAl[(wm + t*16)*32 + lro];
      bfh[t] = *(const s16x8*)&lBh[(wn + t*16)*32 + lro];
      bfl[t] = *(const s16x8*)&lBl[(wn + t*16)*32 + lro];
    }
    #pragma unroll
    for (int mt=0;mt<4;mt++)
      #pragma unroll
      for (int nt=0;nt<4;nt++){
        f32x4 a2 = acc[mt][nt];
        a2 = __builtin_amdgcn_mfma_f32_16x16x32_bf16(afl[mt], bfh[nt], a2, 0,0,0);
        a2 = __builtin_amdgcn_mfma_f32_16x16x32_bf16(afh[mt], bfl[nt], a2, 0,0,0);
        a2 = __builtin_amdgcn_mfma_f32_16x16x32_bf16(afh[mt], bfh[nt], a2, 0,0,0);
        acc[mt][nt] = a2;
      }
  }
  #pragma unroll
  for (int mt=0;mt<4;mt++)
    #pragma unroll
    for (int nt=0;nt<4;nt++){
      const int gn = n0 + wn + nt*16 + (L&15);
      const float bvv = bias[gn];
      const int gmb = m0 + wm + mt*16 + (L>>4)*4;
      #pragma unroll
      for (int r=0;r<4;r++){
        const int gm = gmb + r;
        float v = acc[mt][nt][r] + bvv;
        if (mode==0)      o[(size_t)gm*N + gn] = v;
        else if (mode==1) o[(size_t)gm*N + gn] = fmaxf(v, 0.f);
        else {
          const int b = gm>>11, s = gm&2047, h = gn>>6, d = gn&63;
          o[((size_t)(b*NH+h)*SS + s)*DK + d] = v;
        }
      }
    }
}

// -------------------------------------------------- attention row kernel (v6)
// 4 query rows per block. KT layout [bh][d][s]; thread t covers j = tile*1024+4t..+3.
// Each kv quad is cvt'd to f64 ONCE and feeds 4 rows (cvt/pair 1 -> 0.25,
// loads/pair /4 vs v5). PV shares each V load across 4 row-accumulators.
// eff via exact f64 recurrence u = exp(c*(i0-4t)) * er^row * ce1^e * tstep^tile.
__global__ __launch_bounds__(256) void attn_row(
  const float* __restrict__ q, const float* __restrict__ k, long long qs,
  int bh0, int row0,
  const float* __restrict__ vb, const float* __restrict__ gammas,
  float* __restrict__ att, float* __restrict__ ctx,
  int aw_lo, int aw_hi, int wc)
{
  __shared__ double sq[4][64];
  __shared__ float  p[4][SS];
  __shared__ double red[4][4];      // [wid][row]
  __shared__ float  cpart[4][4][64];// [row][group][d]
  const int i0 = row0 + blockIdx.x*4;
  const int i3 = i0 + 3;
  const int bh = bh0 + blockIdx.y, h = bh&15, b = bh>>4;
  const int wa = (bh >= aw_lo) && (bh < aw_hi);
  const int t = threadIdx.x, wid = t>>6, L = t&63;
  const double c = softplus64(gammas[h]) * (1.0/21.0);

  {
    const int r = t>>6, d = t&63;
    sq[r][d] = (double)q[(size_t)blockIdx.y*qs + (size_t)(i0+r)*DK + d];
  }
  const double ce1   = exp(-c);
  const double er    = exp(c);
  const double tstep = exp(-1024.0 * c);
  double u0 = exp(c * (double)(i0 - 4*t));
  double err0 = 1.0, err1 = er, err2 = er*er, err3 = err2*er;
  __syncthreads();

  const float* kb = k + (size_t)blockIdx.y*qs;   // KT base [d][s]
  double sv[4][8];
  double lmax[4] = {-1e300,-1e300,-1e300,-1e300};
  #pragma unroll
  for (int tile=0; tile<2; tile++){
    const int j0 = tile*1024 + 4*t;
    if (j0 <= i3){
      const float* kcol = kb + j0;
      double acc[4][4];
      #pragma unroll
      for (int r=0;r<4;r++)
        #pragma unroll
        for (int e=0;e<4;e++) acc[r][e] = 0.0;
      #pragma unroll 4
      for (int d=0; d<64; d++){
        f32x4 kv = *(const f32x4*)(kcol + (size_t)d*SS);
        const double k0=(double)kv[0], k1=(double)kv[1];
        const double k2=(double)kv[2], k3=(double)kv[3];
        #pragma unroll
        for (int r=0;r<4;r++){
          const double qd = sq[r][d];
          acc[r][0] = fma(k0, qd, acc[r][0]);
          acc[r][1] = fma(k1, qd, acc[r][1]);
          acc[r][2] = fma(k2, qd, acc[r][2]);
          acc[r][3] = fma(k3, qd, acc[r][3]);
        }
      }
      #pragma unroll
      for (int r=0;r<4;r++){
        double uu = u0 * ((r==0)?err0:(r==1)?err1:(r==2)?err2:err3);
        const int ir = i0 + r;
        #pragma unroll
        for (int e=0;e<4;e++){
          const double ef = ((uu < 1e5) ? uu : 1e5) * 0.125;
          const double s = (j0 + e <= ir) ? acc[r][e]*ef : -1e300;
          sv[r][tile*4+e] = s;
          lmax[r] = (lmax[r] > s) ? lmax[r] : s;
          uu *= ce1;
        }
      }
    }
    u0 *= tstep;
  }
  #pragma unroll
  for (int r=0;r<4;r++){
    double lm = lmax[r];
    #pragma unroll
    for (int m2=1;m2<64;m2<<=1){ double o2 = __shfl_xor(lm,m2,64); lm = (lm>o2)?lm:o2; }
    if (L==0) red[wid][r] = lm;
  }
  __syncthreads();
  double m[4];
  #pragma unroll
  for (int r=0;r<4;r++){
    double mm = red[0][r];
    mm = (mm>red[1][r])?mm:red[1][r];
    mm = (mm>red[2][r])?mm:red[2][r];
    mm = (mm>red[3][r])?mm:red[3][r];
    m[r] = mm;
  }
  __syncthreads();

  // exp (f32) + per-row sum
  float ev[4][8];
  double lsum[4] = {0.0,0.0,0.0,0.0};
  #pragma unroll
  for (int tile=0; tile<2; tile++){
    const int j0 = tile*1024 + 4*t;
    if (j0 <= i3){
      #pragma unroll
      for (int r=0;r<4;r++)
        #pragma unroll
        for (int e=0;e<4;e++){
          float ex = expf((float)(sv[r][tile*4+e] - m[r]));
          ev[r][tile*4+e] = ex;
          lsum[r] += (double)ex;
        }
    }
  }
  #pragma unroll
  for (int r=0;r<4;r++){
    double ls = lsum[r];
    #pragma unroll
    for (int m2=1;m2<64;m2<<=1) ls += __shfl_xor(ls,m2,64);
    if (L==0) red[wid][r] = ls;
  }
  __syncthreads();
  float inv[4];
  #pragma unroll
  for (int r=0;r<4;r++)
    inv[r] = (float)(1.0 / (red[0][r]+red[1][r]+red[2][r]+red[3][r]));
  #pragma unroll
  for (int tile=0; tile<2; tile++){
    const int j0 = tile*1024 + 4*t;
    if (j0 <= i3){
      #pragma unroll
      for (int r=0;r<4;r++){
        f32x4 pv;
        pv[0] = ev[r][tile*4+0]*inv[r]; pv[1] = ev[r][tile*4+1]*inv[r];
        pv[2] = ev[r][tile*4+2]*inv[r]; pv[3] = ev[r][tile*4+3]*inv[r];
        *(f32x4*)&p[r][j0] = pv;
      }
    }
  }
  __syncthreads();

  if (wa){
    #pragma unroll
    for (int r=0;r<4;r++){
      const int ir = i0 + r;
      float* rb = &att[((size_t)bh*SS + ir)*SS];
      for (int jj = t; jj < SS; jj += 256)
        rb[jj] = (jj <= ir) ? p[r][jj] : 0.f;
    }
  }
  if (wc){
    const int gg = t>>6, d = t&63;
    const float* vr = &vb[(size_t)bh*SS*DK + d];
    float ac0[4] = {0.f,0.f,0.f,0.f};
    float ac1[4] = {0.f,0.f,0.f,0.f};
    int jj = gg;
    for (; jj+4 <= i3; jj += 8){
      const float v0 = vr[(size_t)jj*DK];
      const float v1 = vr[(size_t)(jj+4)*DK];
      #pragma unroll
      for (int r=0;r<4;r++){
        ac0[r] = fmaf(p[r][jj],   v0, ac0[r]);
        ac1[r] = fmaf(p[r][jj+4], v1, ac1[r]);
      }
    }
    for (; jj <= i3; jj += 4){
      const float v0 = vr[(size_t)jj*DK];
      #pragma unroll
      for (int r=0;r<4;r++) ac0[r] = fmaf(p[r][jj], v0, ac0[r]);
    }
    #pragma unroll
    for (int r=0;r<4;r++) cpart[r][gg][d] = ac0[r] + ac1[r];
    __syncthreads();
    {
      const int r = t>>6, dd = t&63;
      const float cc = cpart[r][0][dd]+cpart[r][1][dd]+cpart[r][2][dd]+cpart[r][3][dd];
      ctx[((size_t)(b*SS + (i0+r))*NH + h)*DK + dd] = cc;
    }
  }
}

// -------------------------------------------------- corner: bh63 rows 0..127
// src: [Q slice [s][d] | KT slice [d][s]]
__global__ __launch_bounds__(256) void attn_corner(
  const float* __restrict__ src, const float* __restrict__ gammas,
  float* __restrict__ att)
{
  __shared__ float lq[128*64];
  __shared__ float lk[128*64];
  const int t = threadIdx.x;
  for (int idx = t; idx < 128*64; idx += 256)
    lq[idx] = src[idx];                              // Q rows 0..127, [s][d]
  for (int idx = t; idx < 64*128; idx += 256){
    const int d = idx >> 7, s = idx & 127;           // KT[d][s] -> lk[s][d]
    lk[s*64 + d] = src[QKS + (size_t)d*SS + s];
  }
  __syncthreads();
  const double sp = softplus64(gammas[15]);
  const int w = t>>6, L = t&63;
  for (int i = w; i < 128; i += 4){
    double s0 = -1e300, s1 = -1e300;
    if (L <= i){
      double a = 0.0;
      for (int d=0; d<64; d++) a = fma((double)lq[i*64+d], (double)lk[L*64+d], a);
      double eff = exp((double)(i-L)*(1.0/21.0)*sp); eff = (eff<1e5)?eff:1e5;
      s0 = a * 0.125 * eff;
    }
    if (64+L <= i){
      double a = 0.0;
      for (int d=0; d<64; d++) a = fma((double)lq[i*64+d], (double)lk[(64+L)*64+d], a);
      double eff = exp((double)(i-64-L)*(1.0/21.0)*sp); eff = (eff<1e5)?eff:1e5;
      s1 = a * 0.125 * eff;
    }
    double mx = (s0>s1)?s0:s1;
    #pragma unroll
    for (int m2=1;m2<64;m2<<=1){ double o2 = __shfl_xor(mx,m2,64); mx = (mx>o2)?mx:o2; }
    double e0 = (L<=i)    ? exp(s0-mx) : 0.0;
    double e1 = (64+L<=i) ? exp(s1-mx) : 0.0;
    double su = e0+e1;
    #pragma unroll
    for (int m2=1;m2<64;m2<<=1) su += __shfl_xor(su,m2,64);
    const double inv = 1.0/su;
    const float p0 = (float)(e0*inv), p1 = (float)(e1*inv);
    float* rb = &att[((size_t)63*SS + i)*SS];
    #pragma unroll
    for (int tt=0; tt<32; tt++)
      rb[tt*64+L] = (tt==0) ? p0 : (tt==1) ? p1 : 0.f;
  }
}

// -------------------------------------------------- layernorm (f32)
__global__ __launch_bounds__(256) void lnorm(
  const float* __restrict__ a, const float* __restrict__ b,
  const float* __restrict__ sc, const float* __restrict__ bi,
  float* __restrict__ out)
{
  __shared__ float red[4];
  const int row = blockIdx.x, tid = threadIdx.x, wid = tid>>6;
  const size_t rb = (size_t)row*D_MODEL;
  float x[4];
  #pragma unroll
  for (int i=0;i<4;i++){
    const int c = tid + i*256;
    x[i] = a[rb+c] + b[rb+c];
  }
  float s = x[0]+x[1]+x[2]+x[3];
  for (int m2=1;m2<64;m2<<=1) s += __shfl_xor(s,m2,64);
  if ((tid&63)==0) red[wid] = s;
  __syncthreads();
  const float mu = (red[0]+red[1]+red[2]+red[3]) * (1.0f/1024.0f);
  __syncthreads();
  float ss2 = 0.f;
  #pragma unroll
  for (int i=0;i<4;i++){ float d = x[i]-mu; ss2 += d*d; }
  for (int m2=1;m2<64;m2<<=1) ss2 += __shfl_xor(ss2,m2,64);
  if ((tid&63)==0) red[wid] = ss2;
  __syncthreads();
  const float var = (red[0]+red[1]+red[2]+red[3]) * (1.0f/1024.0f);
  const float inv = rsqrtf(var + 1e-5f);
  #pragma unroll
  for (int i=0;i<4;i++){
    const int c = tid + i*256;
    out[rb+c] = (x[i]-mu)*inv*sc[c] + bi[c];
  }
}

// ------------------------------------------------------------------ launch
// Scratch map (inside att output, 64 blocks of 16 MiB):
//   blocks 0-2   : bf16 weight splits
//   blocks 3-4   : vbp  -> then aof
//   blocks 5-6   : ctxb -> then x1f
//   blocks 7-8   : hbuf chunk (FFN M-chunked x4)
//   blocks 9-10  : fbuf
//   blocks 60-61 : QF ([bh][s][d]);  blocks 62-63 : KF (KT: [bh][d][s])
// => fused attention writes att for bh 11..59 in pass A; bh 0..10 deferred,
//    bh 60..63 tail staged via D1/D2 copies (layout-agnostic slices).
extern "C" void kernel_launch(void* const* d_in, const int* in_sizes, int n_in,
                              void* d_out, int out_size, void* d_ws, size_t ws_size,
                              hipStream_t stream)
{
  const float* query  = (const float*)d_in[0];
  const float* key    = (const float*)d_in[1];
  const float* values = (const float*)d_in[2];
  const float* Wk   = (const float*)d_in[3];
  const float* bk   = (const float*)d_in[4];
  const float* Wv   = (const float*)d_in[5];
  const float* bv   = (const float*)d_in[6];
  const float* Wout = (const float*)d_in[7];
  const float* bout = (const float*)d_in[8];
  const float* gammas = (const float*)d_in[9];
  const float* ln1s = (const float*)d_in[10];
  const float* ln1b = (const float*)d_in[11];
  const float* W1   = (const float*)d_in[12];
  const float* b1   = (const float*)d_in[13];
  const float* W2   = (const float*)d_in[14];
  const float* b2   = (const float*)d_in[15];
  const float* ln2s = (const float*)d_in[16];
  const float* ln2b = (const float*)d_in[17];

  float* outx = (float*)d_out;
  float* att  = outx + (size_t)ROWS*D_MODEL;

  char* sc = (char*)att;
  u16* WkTh  = (u16*)(sc +  0*MiB);
  u16* WkTm  = (u16*)(sc +  2*MiB);
  u16* WkTl  = (u16*)(sc +  4*MiB);
  u16* WvTh  = (u16*)(sc +  6*MiB);
  u16* WvTl  = (u16*)(sc +  8*MiB);
  u16* WoTh  = (u16*)(sc + 10*MiB);
  u16* WoTl  = (u16*)(sc + 12*MiB);
  u16* W1Th  = (u16*)(sc + 14*MiB);
  u16* W1Tl  = (u16*)(sc + 22*MiB);
  u16* W2Th  = (u16*)(sc + 30*MiB);
  u16* W2Tl  = (u16*)(sc + 38*MiB);
  float* vbp  = (float*)(sc +  48*MiB);   // blocks 3-4
  float* ctxb = (float*)(sc +  80*MiB);   // blocks 5-6
  float* aof  = (float*)(sc +  48*MiB);   // reuse 3-4 after vbp dead
  float* x1f  = (float*)(sc +  80*MiB);   // reuse 5-6 after ctxb dead
  float* hbuf = (float*)(sc + 112*MiB);   // blocks 7-8 (32 MiB chunk)
  float* fbuf = (float*)(sc + 144*MiB);   // blocks 9-10
  float* QF = att + 60*BHSZ;
  float* KF = att + 62*BHSZ;
  float* D1 = att + 63*BHSZ + 2*(MiB/4)*4;
  float* D2 = att + 63*BHSZ;

  dim3 th(256);
  twc<<<dim3(32,32),  th, 0, stream>>>(Wk,   WkTh, WkTm, WkTl, 1024, 1024);
  twc<<<dim3(32,32),  th, 0, stream>>>(Wv,   WvTh, WvTl, nullptr, 1024, 1024);
  twc<<<dim3(32,32),  th, 0, stream>>>(Wout, WoTh, WoTl, nullptr, 1024, 1024);
  twc<<<dim3(128,32), th, 0, stream>>>(W1,   W1Th, W1Tl, nullptr, 1024, 4096);
  twc<<<dim3(32,128), th, 0, stream>>>(W2,   W2Th, W2Tl, nullptr, 4096, 1024);
  gemm3<<<dim3(8,64), th, 0, stream>>>(query, WkTh, WkTm, WkTl, bk, ROWS, 1024, 1024, 0, QF);
  gemm3<<<dim3(8,64), th, 0, stream>>>(key,   WkTh, WkTm, WkTl, bk, ROWS, 1024, 1024, 1, KF);
  gemm2<<<dim3(8,64), th, 0, stream>>>(values, WvTh, WvTl, bv, ROWS, 1024, 1024, 2, vbp);
  // fused attention: ctx for all 64 bh, att for bh 11..59
  attn_row<<<dim3(SS/4,64), th, 0, stream>>>(QF, KF, (long long)QKS, 0, 0,
                                             vbp, gammas, att, ctxb, 11, 60, 1);
  gemm2<<<dim3(8,64),  th, 0, stream>>>(ctxb, WoTh, WoTl, bout, ROWS, 1024, 1024, 0, aof);
  lnorm<<<dim3(ROWS), th, 0, stream>>>(query, aof, ln1s, ln1b, x1f);
  // FFN, M-chunked x4 so hbuf is 32 MiB
  for (int c = 0; c < 4; ++c){
    gemm2<<<dim3(32,16), th, 0, stream>>>(x1f + (size_t)c*2048*1024, W1Th, W1Tl, b1,
                                          2048, 4096, 1024, 1, hbuf);
    gemm2<<<dim3(8,16),  th, 0, stream>>>(hbuf, W2Th, W2Tl, b2,
                                          2048, 1024, 4096, 0, fbuf + (size_t)c*2048*1024);
  }
  lnorm<<<dim3(ROWS), th, 0, stream>>>(x1f, fbuf, ln2s, ln2b, outx);
  // deferred att for bh 0..10 (scratch regions now dead)
  attn_row<<<dim3(SS/4,11), th, 0, stream>>>(QF, KF, (long long)QKS, 0, 0,
                                             vbp, gammas, att, ctxb, 0, 64, 0);
  // bh 60..63 tail: stage q/k slices out of the regions being written
  copyf<<<dim3(512), th, 0, stream>>>(D1,            QF + 60*QKS, 4*(long long)QKS);
  copyf<<<dim3(512), th, 0, stream>>>(D1 + 4*QKS,    KF + 60*QKS, 4*(long long)QKS);
  attn_row<<<dim3(SS/4,3), th, 0, stream>>>(D1, D1 + 4*QKS, (long long)QKS, 60, 0,
                                            vbp, gammas, att, ctxb, 0, 64, 0);
  attn_row<<<dim3(128,1), th, 0, stream>>>(D1 + 3*QKS, D1 + 7*QKS, 0ll, 63, 1536,
                                           vbp, gammas, att, ctxb, 0, 64, 0);
  copyf<<<dim3(128), th, 0, stream>>>(D2,        D1 + 3*QKS, (long long)QKS);
  copyf<<<dim3(128), th, 0, stream>>>(D2 + QKS,  D1 + 7*QKS, (long long)QKS);
  attn_row<<<dim3(352,1), th, 0, stream>>>(D2, D2 + QKS, 0ll, 63, 128,
                                           vbp, gammas, att, ctxb, 0, 64, 0);
  attn_corner<<<dim3(1), th, 0, stream>>>(D2, gammas, att);
}

// Round 9
// 4383.763 us; speedup vs baseline: 2.3458x; 1.1997x over previous
//
#include <hip/hip_runtime.h>
#include <math.h>

typedef unsigned short u16;
typedef float f32x4 __attribute__((ext_vector_type(4)));
typedef short s16x8 __attribute__((ext_vector_type(8)));

#define D_MODEL 1024
#define NH 16
#define DK 64
#define DFF 4096
#define BB 4
#define SS 2048
#define ROWS (BB*SS)   // 8192
#define MiB 1048576ull
#define BHSZ 4194304ull   // floats per att[bh] block (2048*2048)
#define QKS  131072ull    // floats per bh slice of q/k (2048*64)

static __device__ __forceinline__ float bf2f(u16 v){
  union{unsigned u; float f;} x; x.u = ((unsigned)v)<<16; return x.f;
}
static __device__ __forceinline__ u16 f2bf(float f){
  union{float f; unsigned u;} x; x.f=f;
  unsigned r = x.u + 0x7fffu + ((x.u>>16)&1u);
  return (u16)(r>>16);
}
static __device__ __forceinline__ double softplus64(float gf){
  double g = (double)gf;
  return (g > 0.0) ? g + log1p(exp(-g)) : log1p(exp(g));
}

// -------------------------------------------------- transpose + f32->bf16 split
__global__ __launch_bounds__(256) void twc(const float* __restrict__ in,
    u16* __restrict__ oh, u16* __restrict__ om, u16* __restrict__ ol, int R, int C){
  __shared__ float t[32][33];
  int c0 = blockIdx.x*32, r0 = blockIdx.y*32;
  int tx = threadIdx.x & 31, ty = threadIdx.x >> 5;
  for (int i=ty; i<32; i+=8) t[i][tx] = in[(size_t)(r0+i)*C + c0 + tx];
  __syncthreads();
  for (int i=ty; i<32; i+=8){
    float x = t[tx][i];
    u16 h = f2bf(x);
    size_t o = (size_t)(c0+i)*R + r0 + tx;
    oh[o] = h;
    if (om){
      float r1 = x - bf2f(h);
      u16 m = f2bf(r1);
      om[o] = m;
      if (ol){ float r2 = r1 - bf2f(m); ol[o] = f2bf(r2); }
    }
  }
}

// -------------------------------------------------- f32 copy
__global__ __launch_bounds__(256) void copyf(float* __restrict__ dst,
                                             const float* __restrict__ src, long long n){
  long long i = (long long)blockIdx.x*256 + threadIdx.x;
  long long stride = (long long)gridDim.x*256;
  for (; i < n; i += stride) dst[i] = src[i];
}

// -------------------------------------------------- triple-split GEMM (Q/K proj)
// kt=0: o[bh][s][d] layout; kt=1: o[bh][d][s] (K transposed for attn coalescing)
__global__ __launch_bounds__(256) void gemm3(
    const float* __restrict__ A, const u16* __restrict__ Bh,
    const u16* __restrict__ Bm, const u16* __restrict__ Bl,
    const float* __restrict__ bias, int M, int N, int K, int kt, float* __restrict__ o)
{
  __shared__ u16 lAh[128*32], lAm[128*32], lAl[128*32];
  __shared__ u16 lBh[128*32], lBm[128*32], lBl[128*32];
  const int tid = threadIdx.x, wid = tid>>6, L = tid&63;
  const int m0 = blockIdx.y*128, n0 = blockIdx.x*128;
  const int wm = (wid>>1)*64, wn = (wid&1)*64;
  f32x4 acc[4][4] = {};
  const int srow = wid*32 + (L>>2);
  const int scol = (L&3)*8;
  for (int ktile=0; ktile<K; ktile+=32){
    s16x8 ah[2], am[2], al[2], vbh[2], vbm[2], vbl[2];
    #pragma unroll
    for (int rr=0; rr<2; rr++){
      const float* ap = &A[(size_t)(m0 + srow + rr*16)*K + ktile + scol];
      #pragma unroll
      for (int e=0;e<8;e++){
        float x = ap[e];
        u16 hh = f2bf(x); float r1 = x - bf2f(hh);
        u16 mm = f2bf(r1); float r2 = r1 - bf2f(mm);
        ah[rr][e] = (short)hh; am[rr][e] = (short)mm; al[rr][e] = (short)f2bf(r2);
      }
      const size_t bo = (size_t)(n0 + srow + rr*16)*K + ktile + scol;
      vbh[rr] = *(const s16x8*)&Bh[bo];
      vbm[rr] = *(const s16x8*)&Bm[bo];
      vbl[rr] = *(const s16x8*)&Bl[bo];
    }
    __syncthreads();
    #pragma unroll
    for (int rr=0; rr<2; rr++){
      const int ro = (srow + rr*16)*32 + scol;
      *(s16x8*)&lAh[ro] = ah[rr]; *(s16x8*)&lAm[ro] = am[rr]; *(s16x8*)&lAl[ro] = al[rr];
      *(s16x8*)&lBh[ro] = vbh[rr]; *(s16x8*)&lBm[ro] = vbm[rr]; *(s16x8*)&lBl[ro] = vbl[rr];
    }
    __syncthreads();
    const int lro = (L&15)*32 + (L>>4)*8;
    s16x8 afh[4], afm[4], afl[4], bfh[4], bfm[4], bfl[4];
    #pragma unroll
    for (int t=0;t<4;t++){
      afh[t] = *(const s16x8*)&lAh[(wm + t*16)*32 + lro];
      afm[t] = *(const s16x8*)&lAm[(wm + t*16)*32 + lro];
      afl[t] = *(const s16x8*)&lAl[(wm + t*16)*32 + lro];
      bfh[t] = *(const s16x8*)&lBh[(wn + t*16)*32 + lro];
      bfm[t] = *(const s16x8*)&lBm[(wn + t*16)*32 + lro];
      bfl[t] = *(const s16x8*)&lBl[(wn + t*16)*32 + lro];
    }
    #pragma unroll
    for (int mt=0;mt<4;mt++)
      #pragma unroll
      for (int nt=0;nt<4;nt++){
        f32x4 a2 = acc[mt][nt];
        a2 = __builtin_amdgcn_mfma_f32_16x16x32_bf16(afl[mt], bfh[nt], a2, 0,0,0);
        a2 = __builtin_amdgcn_mfma_f32_16x16x32_bf16(afm[mt], bfm[nt], a2, 0,0,0);
        a2 = __builtin_amdgcn_mfma_f32_16x16x32_bf16(afh[mt], bfl[nt], a2, 0,0,0);
        a2 = __builtin_amdgcn_mfma_f32_16x16x32_bf16(afm[mt], bfh[nt], a2, 0,0,0);
        a2 = __builtin_amdgcn_mfma_f32_16x16x32_bf16(afh[mt], bfm[nt], a2, 0,0,0);
        a2 = __builtin_amdgcn_mfma_f32_16x16x32_bf16(afh[mt], bfh[nt], a2, 0,0,0);
        acc[mt][nt] = a2;
      }
  }
  #pragma unroll
  for (int mt=0;mt<4;mt++)
    #pragma unroll
    for (int nt=0;nt<4;nt++){
      const int gn = n0 + wn + nt*16 + (L&15);
      const float bvv = bias[gn];
      const int gmb = m0 + wm + mt*16 + (L>>4)*4;
      const int h = gn>>6, d = gn&63;
      #pragma unroll
      for (int r=0;r<4;r++){
        const int gm = gmb + r, b = gm>>11, s = gm&2047;
        const float v = acc[mt][nt][r] + bvv;
        if (kt) o[((size_t)(b*NH+h)*DK + d)*SS + s] = v;
        else    o[((size_t)(b*NH+h)*SS + s)*DK + d] = v;
      }
    }
}

// -------------------------------------------------- pair-split GEMM (~f32 quality)
__global__ __launch_bounds__(256) void gemm2(
    const float* __restrict__ A, const u16* __restrict__ Bh, const u16* __restrict__ Bl,
    const float* __restrict__ bias, int M, int N, int K, int mode, float* __restrict__ o)
{
  __shared__ u16 lAh[128*32], lAl[128*32], lBh[128*32], lBl[128*32];
  const int tid = threadIdx.x, wid = tid>>6, L = tid&63;
  const int m0 = blockIdx.y*128, n0 = blockIdx.x*128;
  const int wm = (wid>>1)*64, wn = (wid&1)*64;
  f32x4 acc[4][4] = {};
  const int srow = wid*32 + (L>>2);
  const int scol = (L&3)*8;
  for (int kt=0; kt<K; kt+=32){
    s16x8 ah[2], al[2], vbh[2], vbl[2];
    #pragma unroll
    for (int rr=0; rr<2; rr++){
      const float* ap = &A[(size_t)(m0 + srow + rr*16)*K + kt + scol];
      #pragma unroll
      for (int e=0;e<8;e++){
        float x = ap[e];
        u16 hh = f2bf(x);
        ah[rr][e] = (short)hh;
        al[rr][e] = (short)f2bf(x - bf2f(hh));
      }
      const size_t bo = (size_t)(n0 + srow + rr*16)*K + kt + scol;
      vbh[rr] = *(const s16x8*)&Bh[bo];
      vbl[rr] = *(const s16x8*)&Bl[bo];
    }
    __syncthreads();
    #pragma unroll
    for (int rr=0; rr<2; rr++){
      const int ro = (srow + rr*16)*32 + scol;
      *(s16x8*)&lAh[ro] = ah[rr]; *(s16x8*)&lAl[ro] = al[rr];
      *(s16x8*)&lBh[ro] = vbh[rr]; *(s16x8*)&lBl[ro] = vbl[rr];
    }
    __syncthreads();
    const int lro = (L&15)*32 + (L>>4)*8;
    s16x8 afh[4], afl[4], bfh[4], bfl[4];
    #pragma unroll
    for (int t=0;t<4;t++){
      afh[t] = *(const s16x8*)&lAh[(wm + t*16)*32 + lro];
      afl[t] = *(const s16x8*)&lAl[(wm + t*16)*32 + lro];
      bfh[t] = *(const s16x8*)&lBh[(wn + t*16)*32 + lro];
      bfl[t] = *(const s16x8*)&lBl[(wn + t*16)*32 + lro];
    }
    #pragma unroll
    for (int mt=0;mt<4;mt++)
      #pragma unroll
      for (int nt=0;nt<4;nt++){
        f32x4 a2 = acc[mt][nt];
        a2 = __builtin_amdgcn_mfma_f32_16x16x32_bf16(afl[mt], bfh[nt], a2, 0,0,0);
        a2 = __builtin_amdgcn_mfma_f32_16x16x32_bf16(afh[mt], bfl[nt], a2, 0,0,0);
        a2 = __builtin_amdgcn_mfma_f32_16x16x32_bf16(afh[mt], bfh[nt], a2, 0,0,0);
        acc[mt][nt] = a2;
      }
  }
  #pragma unroll
  for (int mt=0;mt<4;mt++)
    #pragma unroll
    for (int nt=0;nt<4;nt++){
      const int gn = n0 + wn + nt*16 + (L&15);
      const float bvv = bias[gn];
      const int gmb = m0 + wm + mt*16 + (L>>4)*4;
      #pragma unroll
      for (int r=0;r<4;r++){
        const int gm = gmb + r;
        float v = acc[mt][nt][r] + bvv;
        if (mode==0)      o[(size_t)gm*N + gn] = v;
        else if (mode==1) o[(size_t)gm*N + gn] = fmaxf(v, 0.f);
        else {
          const int b = gm>>11, s = gm&2047, h = gn>>6, d = gn&63;
          o[((size_t)(b*NH+h)*SS + s)*DK + d] = v;
        }
      }
    }
}

// -------------------------------------------------- attention row kernel (v7)
// 4 query rows per block, KT layout. Changes vs v6:
//  - p staged per 1024-tile (LDS 39.4K -> ~22.7K => 7 blocks/CU).
//    PV accumulators persist across tiles; 1024 % 8 == 0 keeps the exact
//    mod-8 accumulator assignment and order -> bit-identical ctx.
//  - att written directly from ev*inv registers as f32x4 (no LDS round-trip).
__global__ __launch_bounds__(256) void attn_row(
  const float* __restrict__ q, const float* __restrict__ k, long long qs,
  int bh0, int row0,
  const float* __restrict__ vb, const float* __restrict__ gammas,
  float* __restrict__ att, float* __restrict__ ctx,
  int aw_lo, int aw_hi, int wc)
{
  __shared__ double sq[4][64];
  __shared__ float  p[4][1024];     // per-tile staging (PV cross-thread reads)
  __shared__ double red[4][4];      // [wid][row]
  __shared__ float  cpart[4][4][64];// [row][group][d]
  const int i0 = row0 + blockIdx.x*4;
  const int i3 = i0 + 3;
  const int bh = bh0 + blockIdx.y, h = bh&15, b = bh>>4;
  const int wa = (bh >= aw_lo) && (bh < aw_hi);
  const int t = threadIdx.x, wid = t>>6, L = t&63;
  const double c = softplus64(gammas[h]) * (1.0/21.0);

  {
    const int r = t>>6, d = t&63;
    sq[r][d] = (double)q[(size_t)blockIdx.y*qs + (size_t)(i0+r)*DK + d];
  }
  const double ce1   = exp(-c);
  const double er    = exp(c);
  const double tstep = exp(-1024.0 * c);
  double u0 = exp(c * (double)(i0 - 4*t));
  double err1 = er, err2 = er*er, err3 = err2*er;
  __syncthreads();

  const float* kb = k + (size_t)blockIdx.y*qs;   // KT base [d][s]
  double sv[4][8];
  double lmax[4] = {-1e300,-1e300,-1e300,-1e300};
  #pragma unroll
  for (int tile=0; tile<2; tile++){
    const int j0 = tile*1024 + 4*t;
    if (j0 <= i3){
      const float* kcol = kb + j0;
      double acc[4][4];
      #pragma unroll
      for (int r=0;r<4;r++)
        #pragma unroll
        for (int e=0;e<4;e++) acc[r][e] = 0.0;
      #pragma unroll 4
      for (int d=0; d<64; d++){
        f32x4 kv = *(const f32x4*)(kcol + (size_t)d*SS);
        const double k0=(double)kv[0], k1=(double)kv[1];
        const double k2=(double)kv[2], k3=(double)kv[3];
        #pragma unroll
        for (int r=0;r<4;r++){
          const double qd = sq[r][d];
          acc[r][0] = fma(k0, qd, acc[r][0]);
          acc[r][1] = fma(k1, qd, acc[r][1]);
          acc[r][2] = fma(k2, qd, acc[r][2]);
          acc[r][3] = fma(k3, qd, acc[r][3]);
        }
      }
      #pragma unroll
      for (int r=0;r<4;r++){
        double uu = u0 * ((r==0)?1.0:(r==1)?err1:(r==2)?err2:err3);
        const int ir = i0 + r;
        #pragma unroll
        for (int e=0;e<4;e++){
          const double ef = ((uu < 1e5) ? uu : 1e5) * 0.125;
          const double s = (j0 + e <= ir) ? acc[r][e]*ef : -1e300;
          sv[r][tile*4+e] = s;
          lmax[r] = (lmax[r] > s) ? lmax[r] : s;
          uu *= ce1;
        }
      }
    }
    u0 *= tstep;
  }
  #pragma unroll
  for (int r=0;r<4;r++){
    double lm = lmax[r];
    #pragma unroll
    for (int m2=1;m2<64;m2<<=1){ double o2 = __shfl_xor(lm,m2,64); lm = (lm>o2)?lm:o2; }
    if (L==0) red[wid][r] = lm;
  }
  __syncthreads();
  double m[4];
  #pragma unroll
  for (int r=0;r<4;r++){
    double mm = red[0][r];
    mm = (mm>red[1][r])?mm:red[1][r];
    mm = (mm>red[2][r])?mm:red[2][r];
    mm = (mm>red[3][r])?mm:red[3][r];
    m[r] = mm;
  }
  __syncthreads();

  // exp (f32) + per-row sum
  float ev[4][8];
  double lsum[4] = {0.0,0.0,0.0,0.0};
  #pragma unroll
  for (int tile=0; tile<2; tile++){
    const int j0 = tile*1024 + 4*t;
    if (j0 <= i3){
      #pragma unroll
      for (int r=0;r<4;r++)
        #pragma unroll
        for (int e=0;e<4;e++){
          float ex = expf((float)(sv[r][tile*4+e] - m[r]));
          ev[r][tile*4+e] = ex;
          lsum[r] += (double)ex;
        }
    }
  }
  #pragma unroll
  for (int r=0;r<4;r++){
    double ls = lsum[r];
    #pragma unroll
    for (int m2=1;m2<64;m2<<=1) ls += __shfl_xor(ls,m2,64);
    if (L==0) red[wid][r] = ls;
  }
  __syncthreads();
  float inv[4];
  #pragma unroll
  for (int r=0;r<4;r++)
    inv[r] = (float)(1.0 / (red[0][r]+red[1][r]+red[2][r]+red[3][r]));

  // per-tile: stage p (wc), att-write from regs (wa), PV accumulate (wc)
  float ac0[4] = {0.f,0.f,0.f,0.f};
  float ac1[4] = {0.f,0.f,0.f,0.f};
  const int gg = t>>6, d = t&63;
  const float* vr = &vb[(size_t)bh*SS*DK + d];
  #pragma unroll
  for (int tile=0; tile<2; tile++){
    const int base = tile*1024;
    const int j0 = base + 4*t;
    if (wc){
      if (tile) __syncthreads();     // prior tile's PV readers done
      if (j0 <= i3){
        #pragma unroll
        for (int r=0;r<4;r++){
          f32x4 pv;
          pv[0] = ev[r][tile*4+0]*inv[r]; pv[1] = ev[r][tile*4+1]*inv[r];
          pv[2] = ev[r][tile*4+2]*inv[r]; pv[3] = ev[r][tile*4+3]*inv[r];
          *(f32x4*)&p[r][4*t] = pv;
        }
      }
      __syncthreads();
    }
    if (wa){
      const int jj = 4*t;
      #pragma unroll
      for (int r=0;r<4;r++){
        const int ir = i0 + r;
        float* rb = &att[((size_t)bh*SS + ir)*SS + base];
        const float iv = inv[r];
        f32x4 o;
        o[0] = (base+jj   <= ir) ? ev[r][tile*4+0]*iv : 0.f;
        o[1] = (base+jj+1 <= ir) ? ev[r][tile*4+1]*iv : 0.f;
        o[2] = (base+jj+2 <= ir) ? ev[r][tile*4+2]*iv : 0.f;
        o[3] = (base+jj+3 <= ir) ? ev[r][tile*4+3]*iv : 0.f;
        *(f32x4*)&rb[jj] = o;
      }
    }
    if (wc){
      int hi = i3 - base; if (hi > 1023) hi = 1023;
      const float* vt = vr + (size_t)base*DK;
      int jj = gg;
      for (; jj+4 <= hi; jj += 8){
        const float v0 = vt[(size_t)jj*DK];
        const float v1 = vt[(size_t)(jj+4)*DK];
        #pragma unroll
        for (int r=0;r<4;r++){
          ac0[r] = fmaf(p[r][jj],   v0, ac0[r]);
          ac1[r] = fmaf(p[r][jj+4], v1, ac1[r]);
        }
      }
      for (; jj <= hi; jj += 4){
        const float v0 = vt[(size_t)jj*DK];
        #pragma unroll
        for (int r=0;r<4;r++) ac0[r] = fmaf(p[r][jj], v0, ac0[r]);
      }
    }
  }
  if (wc){
    #pragma unroll
    for (int r=0;r<4;r++) cpart[r][gg][d] = ac0[r] + ac1[r];
    __syncthreads();
    {
      const int r = t>>6, dd = t&63;
      const float cc = cpart[r][0][dd]+cpart[r][1][dd]+cpart[r][2][dd]+cpart[r][3][dd];
      ctx[((size_t)(b*SS + (i0+r))*NH + h)*DK + dd] = cc;
    }
  }
}

// -------------------------------------------------- corner: bh63 rows 0..127
// src: [Q slice [s][d] | KT slice [d][s]]   (fallback path only)
__global__ __launch_bounds__(256) void attn_corner(
  const float* __restrict__ src, const float* __restrict__ gammas,
  float* __restrict__ att)
{
  __shared__ float lq[128*64];
  __shared__ float lk[128*64];
  const int t = threadIdx.x;
  for (int idx = t; idx < 128*64; idx += 256)
    lq[idx] = src[idx];                              // Q rows 0..127, [s][d]
  for (int idx = t; idx < 64*128; idx += 256){
    const int d = idx >> 7, s = idx & 127;           // KT[d][s] -> lk[s][d]
    lk[s*64 + d] = src[QKS + (size_t)d*SS + s];
  }
  __syncthreads();
  const double sp = softplus64(gammas[15]);
  const int w = t>>6, L = t&63;
  for (int i = w; i < 128; i += 4){
    double s0 = -1e300, s1 = -1e300;
    if (L <= i){
      double a = 0.0;
      for (int d=0; d<64; d++) a = fma((double)lq[i*64+d], (double)lk[L*64+d], a);
      double eff = exp((double)(i-L)*(1.0/21.0)*sp); eff = (eff<1e5)?eff:1e5;
      s0 = a * 0.125 * eff;
    }
    if (64+L <= i){
      double a = 0.0;
      for (int d=0; d<64; d++) a = fma((double)lq[i*64+d], (double)lk[(64+L)*64+d], a);
      double eff = exp((double)(i-64-L)*(1.0/21.0)*sp); eff = (eff<1e5)?eff:1e5;
      s1 = a * 0.125 * eff;
    }
    double mx = (s0>s1)?s0:s1;
    #pragma unroll
    for (int m2=1;m2<64;m2<<=1){ double o2 = __shfl_xor(mx,m2,64); mx = (mx>o2)?mx:o2; }
    double e0 = (L<=i)    ? exp(s0-mx) : 0.0;
    double e1 = (64+L<=i) ? exp(s1-mx) : 0.0;
    double su = e0+e1;
    #pragma unroll
    for (int m2=1;m2<64;m2<<=1) su += __shfl_xor(su,m2,64);
    const double inv = 1.0/su;
    const float p0 = (float)(e0*inv), p1 = (float)(e1*inv);
    float* rb = &att[((size_t)63*SS + i)*SS];
    #pragma unroll
    for (int tt=0; tt<32; tt++)
      rb[tt*64+L] = (tt==0) ? p0 : (tt==1) ? p1 : 0.f;
  }
}

// -------------------------------------------------- layernorm (f32)
__global__ __launch_bounds__(256) void lnorm(
  const float* __restrict__ a, const float* __restrict__ b,
  const float* __restrict__ sc, const float* __restrict__ bi,
  float* __restrict__ out)
{
  __shared__ float red[4];
  const int row = blockIdx.x, tid = threadIdx.x, wid = tid>>6;
  const size_t rb = (size_t)row*D_MODEL;
  float x[4];
  #pragma unroll
  for (int i=0;i<4;i++){
    const int c = tid + i*256;
    x[i] = a[rb+c] + b[rb+c];
  }
  float s = x[0]+x[1]+x[2]+x[3];
  for (int m2=1;m2<64;m2<<=1) s += __shfl_xor(s,m2,64);
  if ((tid&63)==0) red[wid] = s;
  __syncthreads();
  const float mu = (red[0]+red[1]+red[2]+red[3]) * (1.0f/1024.0f);
  __syncthreads();
  float ss2 = 0.f;
  #pragma unroll
  for (int i=0;i<4;i++){ float d = x[i]-mu; ss2 += d*d; }
  for (int m2=1;m2<64;m2<<=1) ss2 += __shfl_xor(ss2,m2,64);
  if ((tid&63)==0) red[wid] = ss2;
  __syncthreads();
  const float var = (red[0]+red[1]+red[2]+red[3]) * (1.0f/1024.0f);
  const float inv = rsqrtf(var + 1e-5f);
  #pragma unroll
  for (int i=0;i<4;i++){
    const int c = tid + i*256;
    out[rb+c] = (x[i]-mu)*inv*sc[c] + bi[c];
  }
}

// ------------------------------------------------------------------ launch
// If ws_size >= 240 MiB: ALL scratch lives in d_ws; the single attention
// pass fuses ctx + att for all 64 bh (no deferred pass, no copies, no corner).
// Otherwise: fall back to the aliased-into-att schedule (blocks 0-10 scratch,
// 60-63 QF/KF; att bh 11..59 fused, 0..10 deferred, 60..63 staged tail).
extern "C" void kernel_launch(void* const* d_in, const int* in_sizes, int n_in,
                              void* d_out, int out_size, void* d_ws, size_t ws_size,
                              hipStream_t stream)
{
  const float* query  = (const float*)d_in[0];
  const float* key    = (const float*)d_in[1];
  const float* values = (const float*)d_in[2];
  const float* Wk   = (const float*)d_in[3];
  const float* bk   = (const float*)d_in[4];
  const float* Wv   = (const float*)d_in[5];
  const float* bv   = (const float*)d_in[6];
  const float* Wout = (const float*)d_in[7];
  const float* bout = (const float*)d_in[8];
  const float* gammas = (const float*)d_in[9];
  const float* ln1s = (const float*)d_in[10];
  const float* ln1b = (const float*)d_in[11];
  const float* W1   = (const float*)d_in[12];
  const float* b1   = (const float*)d_in[13];
  const float* W2   = (const float*)d_in[14];
  const float* b2   = (const float*)d_in[15];
  const float* ln2s = (const float*)d_in[16];
  const float* ln2b = (const float*)d_in[17];

  float* outx = (float*)d_out;
  float* att  = outx + (size_t)ROWS*D_MODEL;

  const bool usews = (d_ws != nullptr) && (ws_size >= 240ull*MiB);
  char* sc = usews ? (char*)d_ws : (char*)att;
  u16* WkTh  = (u16*)(sc +  0*MiB);
  u16* WkTm  = (u16*)(sc +  2*MiB);
  u16* WkTl  = (u16*)(sc +  4*MiB);
  u16* WvTh  = (u16*)(sc +  6*MiB);
  u16* WvTl  = (u16*)(sc +  8*MiB);
  u16* WoTh  = (u16*)(sc + 10*MiB);
  u16* WoTl  = (u16*)(sc + 12*MiB);
  u16* W1Th  = (u16*)(sc + 14*MiB);
  u16* W1Tl  = (u16*)(sc + 22*MiB);
  u16* W2Th  = (u16*)(sc + 30*MiB);
  u16* W2Tl  = (u16*)(sc + 38*MiB);
  float* vbp  = (float*)(sc +  48*MiB);
  float* ctxb = (float*)(sc +  80*MiB);
  float* aof  = (float*)(sc +  48*MiB);   // reuse after vbp dead
  float* x1f  = (float*)(sc +  80*MiB);   // reuse after ctxb dead
  float* hbuf = (float*)(sc + 112*MiB);
  float* fbuf = (float*)(sc + 144*MiB);
  float* QF = usews ? (float*)(sc + 176*MiB) : att + 60*BHSZ;
  float* KF = usews ? (float*)(sc + 208*MiB) : att + 62*BHSZ;
  float* D1 = att + 63*BHSZ + 2*(MiB/4)*4;
  float* D2 = att + 63*BHSZ;

  dim3 th(256);
  twc<<<dim3(32,32),  th, 0, stream>>>(Wk,   WkTh, WkTm, WkTl, 1024, 1024);
  twc<<<dim3(32,32),  th, 0, stream>>>(Wv,   WvTh, WvTl, nullptr, 1024, 1024);
  twc<<<dim3(32,32),  th, 0, stream>>>(Wout, WoTh, WoTl, nullptr, 1024, 1024);
  twc<<<dim3(128,32), th, 0, stream>>>(W1,   W1Th, W1Tl, nullptr, 1024, 4096);
  twc<<<dim3(32,128), th, 0, stream>>>(W2,   W2Th, W2Tl, nullptr, 4096, 1024);
  gemm3<<<dim3(8,64), th, 0, stream>>>(query, WkTh, WkTm, WkTl, bk, ROWS, 1024, 1024, 0, QF);
  gemm3<<<dim3(8,64), th, 0, stream>>>(key,   WkTh, WkTm, WkTl, bk, ROWS, 1024, 1024, 1, KF);
  gemm2<<<dim3(8,64), th, 0, stream>>>(values, WvTh, WvTl, bv, ROWS, 1024, 1024, 2, vbp);
  if (usews){
    // one fused pass: ctx + att for all 64 bh
    attn_row<<<dim3(SS/4,64), th, 0, stream>>>(QF, KF, (long long)QKS, 0, 0,
                                               vbp, gammas, att, ctxb, 0, 64, 1);
  } else {
    attn_row<<<dim3(SS/4,64), th, 0, stream>>>(QF, KF, (long long)QKS, 0, 0,
                                               vbp, gammas, att, ctxb, 11, 60, 1);
  }
  gemm2<<<dim3(8,64),  th, 0, stream>>>(ctxb, WoTh, WoTl, bout, ROWS, 1024, 1024, 0, aof);
  lnorm<<<dim3(ROWS), th, 0, stream>>>(query, aof, ln1s, ln1b, x1f);
  // FFN, M-chunked x4 so hbuf is 32 MiB
  for (int c = 0; c < 4; ++c){
    gemm2<<<dim3(32,16), th, 0, stream>>>(x1f + (size_t)c*2048*1024, W1Th, W1Tl, b1,
                                          2048, 4096, 1024, 1, hbuf);
    gemm2<<<dim3(8,16),  th, 0, stream>>>(hbuf, W2Th, W2Tl, b2,
                                          2048, 1024, 4096, 0, fbuf + (size_t)c*2048*1024);
  }
  lnorm<<<dim3(ROWS), th, 0, stream>>>(x1f, fbuf, ln2s, ln2b, outx);
  if (!usews){
    // deferred att for bh 0..10 (scratch regions now dead)
    attn_row<<<dim3(SS/4,11), th, 0, stream>>>(QF, KF, (long long)QKS, 0, 0,
                                               vbp, gammas, att, ctxb, 0, 64, 0);
    // bh 60..63 tail: stage q/k slices out of the regions being written
    copyf<<<dim3(512), th, 0, stream>>>(D1,            QF + 60*QKS, 4*(long long)QKS);
    copyf<<<dim3(512), th, 0, stream>>>(D1 + 4*QKS,    KF + 60*QKS, 4*(long long)QKS);
    attn_row<<<dim3(SS/4,3), th, 0, stream>>>(D1, D1 + 4*QKS, (long long)QKS, 60, 0,
                                              vbp, gammas, att, ctxb, 0, 64, 0);
    attn_row<<<dim3(128,1), th, 0, stream>>>(D1 + 3*QKS, D1 + 7*QKS, 0ll, 63, 1536,
                                             vbp, gammas, att, ctxb, 0, 64, 0);
    copyf<<<dim3(128), th, 0, stream>>>(D2,        D1 + 3*QKS, (long long)QKS);
    copyf<<<dim3(128), th, 0, stream>>>(D2 + QKS,  D1 + 7*QKS, (long long)QKS);
    attn_row<<<dim3(352,1), th, 0, stream>>>(D2, D2 + QKS, 0ll, 63, 128,
                                             vbp, gammas, att, ctxb, 0, 64, 0);
    attn_corner<<<dim3(1), th, 0, stream>>>(D2, gammas, att);
  }
}

// Round 10
// 4379.246 us; speedup vs baseline: 2.3482x; 1.0010x over previous
//
#include <hip/hip_runtime.h>
#include <math.h>

typedef unsigned short u16;
typedef float f32x4 __attribute__((ext_vector_type(4)));
typedef short s16x8 __attribute__((ext_vector_type(8)));

#define D_MODEL 1024
#define NH 16
#define DK 64
#define DFF 4096
#define BB 4
#define SS 2048
#define ROWS (BB*SS)   // 8192
#define MiB 1048576ull
#define BHSZ 4194304ull   // floats per att[bh] block (2048*2048)
#define QKS  131072ull    // floats per bh slice of q/k (2048*64)

static __device__ __forceinline__ float bf2f(u16 v){
  union{unsigned u; float f;} x; x.u = ((unsigned)v)<<16; return x.f;
}
static __device__ __forceinline__ u16 f2bf(float f){
  union{float f; unsigned u;} x; x.f=f;
  unsigned r = x.u + 0x7fffu + ((x.u>>16)&1u);
  return (u16)(r>>16);
}
static __device__ __forceinline__ double softplus64(float gf){
  double g = (double)gf;
  return (g > 0.0) ? g + log1p(exp(-g)) : log1p(exp(g));
}

// -------------------------------------------------- transpose + f32->bf16 split
__global__ __launch_bounds__(256) void twc(const float* __restrict__ in,
    u16* __restrict__ oh, u16* __restrict__ om, u16* __restrict__ ol, int R, int C){
  __shared__ float t[32][33];
  int c0 = blockIdx.x*32, r0 = blockIdx.y*32;
  int tx = threadIdx.x & 31, ty = threadIdx.x >> 5;
  for (int i=ty; i<32; i+=8) t[i][tx] = in[(size_t)(r0+i)*C + c0 + tx];
  __syncthreads();
  for (int i=ty; i<32; i+=8){
    float x = t[tx][i];
    u16 h = f2bf(x);
    size_t o = (size_t)(c0+i)*R + r0 + tx;
    oh[o] = h;
    if (om){
      float r1 = x - bf2f(h);
      u16 m = f2bf(r1);
      om[o] = m;
      if (ol){ float r2 = r1 - bf2f(m); ol[o] = f2bf(r2); }
    }
  }
}

// -------------------------------------------------- f32 copy
__global__ __launch_bounds__(256) void copyf(float* __restrict__ dst,
                                             const float* __restrict__ src, long long n){
  long long i = (long long)blockIdx.x*256 + threadIdx.x;
  long long stride = (long long)gridDim.x*256;
  for (; i < n; i += stride) dst[i] = src[i];
}

// -------------------------------------------------- triple-split GEMM (Q/K proj)
// kt=0: o[bh][s][d] layout; kt=1: o[bh][d][s] (K transposed for attn coalescing)
__global__ __launch_bounds__(256) void gemm3(
    const float* __restrict__ A, const u16* __restrict__ Bh,
    const u16* __restrict__ Bm, const u16* __restrict__ Bl,
    const float* __restrict__ bias, int M, int N, int K, int kt, float* __restrict__ o)
{
  __shared__ u16 lAh[128*32], lAm[128*32], lAl[128*32];
  __shared__ u16 lBh[128*32], lBm[128*32], lBl[128*32];
  const int tid = threadIdx.x, wid = tid>>6, L = tid&63;
  const int m0 = blockIdx.y*128, n0 = blockIdx.x*128;
  const int wm = (wid>>1)*64, wn = (wid&1)*64;
  f32x4 acc[4][4] = {};
  const int srow = wid*32 + (L>>2);
  const int scol = (L&3)*8;
  for (int ktile=0; ktile<K; ktile+=32){
    s16x8 ah[2], am[2], al[2], vbh[2], vbm[2], vbl[2];
    #pragma unroll
    for (int rr=0; rr<2; rr++){
      const float* ap = &A[(size_t)(m0 + srow + rr*16)*K + ktile + scol];
      #pragma unroll
      for (int e=0;e<8;e++){
        float x = ap[e];
        u16 hh = f2bf(x); float r1 = x - bf2f(hh);
        u16 mm = f2bf(r1); float r2 = r1 - bf2f(mm);
        ah[rr][e] = (short)hh; am[rr][e] = (short)mm; al[rr][e] = (short)f2bf(r2);
      }
      const size_t bo = (size_t)(n0 + srow + rr*16)*K + ktile + scol;
      vbh[rr] = *(const s16x8*)&Bh[bo];
      vbm[rr] = *(const s16x8*)&Bm[bo];
      vbl[rr] = *(const s16x8*)&Bl[bo];
    }
    __syncthreads();
    #pragma unroll
    for (int rr=0; rr<2; rr++){
      const int ro = (srow + rr*16)*32 + scol;
      *(s16x8*)&lAh[ro] = ah[rr]; *(s16x8*)&lAm[ro] = am[rr]; *(s16x8*)&lAl[ro] = al[rr];
      *(s16x8*)&lBh[ro] = vbh[rr]; *(s16x8*)&lBm[ro] = vbm[rr]; *(s16x8*)&lBl[ro] = vbl[rr];
    }
    __syncthreads();
    const int lro = (L&15)*32 + (L>>4)*8;
    s16x8 afh[4], afm[4], afl[4], bfh[4], bfm[4], bfl[4];
    #pragma unroll
    for (int t=0;t<4;t++){
      afh[t] = *(const s16x8*)&lAh[(wm + t*16)*32 + lro];
      afm[t] = *(const s16x8*)&lAm[(wm + t*16)*32 + lro];
      afl[t] = *(const s16x8*)&lAl[(wm + t*16)*32 + lro];
      bfh[t] = *(const s16x8*)&lBh[(wn + t*16)*32 + lro];
      bfm[t] = *(const s16x8*)&lBm[(wn + t*16)*32 + lro];
      bfl[t] = *(const s16x8*)&lBl[(wn + t*16)*32 + lro];
    }
    #pragma unroll
    for (int mt=0;mt<4;mt++)
      #pragma unroll
      for (int nt=0;nt<4;nt++){
        f32x4 a2 = acc[mt][nt];
        a2 = __builtin_amdgcn_mfma_f32_16x16x32_bf16(afl[mt], bfh[nt], a2, 0,0,0);
        a2 = __builtin_amdgcn_mfma_f32_16x16x32_bf16(afm[mt], bfm[nt], a2, 0,0,0);
        a2 = __builtin_amdgcn_mfma_f32_16x16x32_bf16(afh[mt], bfl[nt], a2, 0,0,0);
        a2 = __builtin_amdgcn_mfma_f32_16x16x32_bf16(afm[mt], bfh[nt], a2, 0,0,0);
        a2 = __builtin_amdgcn_mfma_f32_16x16x32_bf16(afh[mt], bfm[nt], a2, 0,0,0);
        a2 = __builtin_amdgcn_mfma_f32_16x16x32_bf16(afh[mt], bfh[nt], a2, 0,0,0);
        acc[mt][nt] = a2;
      }
  }
  #pragma unroll
  for (int mt=0;mt<4;mt++)
    #pragma unroll
    for (int nt=0;nt<4;nt++){
      const int gn = n0 + wn + nt*16 + (L&15);
      const float bvv = bias[gn];
      const int gmb = m0 + wm + mt*16 + (L>>4)*4;
      const int h = gn>>6, d = gn&63;
      #pragma unroll
      for (int r=0;r<4;r++){
        const int gm = gmb + r, b = gm>>11, s = gm&2047;
        const float v = acc[mt][nt][r] + bvv;
        if (kt) o[((size_t)(b*NH+h)*DK + d)*SS + s] = v;
        else    o[((size_t)(b*NH+h)*SS + s)*DK + d] = v;
      }
    }
}

// -------------------------------------------------- pair-split GEMM (~f32 quality)
__global__ __launch_bounds__(256) void gemm2(
    const float* __restrict__ A, const u16* __restrict__ Bh, const u16* __restrict__ Bl,
    const float* __restrict__ bias, int M, int N, int K, int mode, float* __restrict__ o)
{
  __shared__ u16 lAh[128*32], lAl[128*32], lBh[128*32], lBl[128*32];
  const int tid = threadIdx.x, wid = tid>>6, L = tid&63;
  const int m0 = blockIdx.y*128, n0 = blockIdx.x*128;
  const int wm = (wid>>1)*64, wn = (wid&1)*64;
  f32x4 acc[4][4] = {};
  const int srow = wid*32 + (L>>2);
  const int scol = (L&3)*8;
  for (int kt=0; kt<K; kt+=32){
    s16x8 ah[2], al[2], vbh[2], vbl[2];
    #pragma unroll
    for (int rr=0; rr<2; rr++){
      const float* ap = &A[(size_t)(m0 + srow + rr*16)*K + kt + scol];
      #pragma unroll
      for (int e=0;e<8;e++){
        float x = ap[e];
        u16 hh = f2bf(x);
        ah[rr][e] = (short)hh;
        al[rr][e] = (short)f2bf(x - bf2f(hh));
      }
      const size_t bo = (size_t)(n0 + srow + rr*16)*K + kt + scol;
      vbh[rr] = *(const s16x8*)&Bh[bo];
      vbl[rr] = *(const s16x8*)&Bl[bo];
    }
    __syncthreads();
    #pragma unroll
    for (int rr=0; rr<2; rr++){
      const int ro = (srow + rr*16)*32 + scol;
      *(s16x8*)&lAh[ro] = ah[rr]; *(s16x8*)&lAl[ro] = al[rr];
      *(s16x8*)&lBh[ro] = vbh[rr]; *(s16x8*)&lBl[ro] = vbl[rr];
    }
    __syncthreads();
    const int lro = (L&15)*32 + (L>>4)*8;
    s16x8 afh[4], afl[4], bfh[4], bfl[4];
    #pragma unroll
    for (int t=0;t<4;t++){
      afh[t] = *(const s16x8*)&lAh[(wm + t*16)*32 + lro];
      afl[t] = *(const s16x8*)&lAl[(wm + t*16)*32 + lro];
      bfh[t] = *(const s16x8*)&lBh[(wn + t*16)*32 + lro];
      bfl[t] = *(const s16x8*)&lBl[(wn + t*16)*32 + lro];
    }
    #pragma unroll
    for (int mt=0;mt<4;mt++)
      #pragma unroll
      for (int nt=0;nt<4;nt++){
        f32x4 a2 = acc[mt][nt];
        a2 = __builtin_amdgcn_mfma_f32_16x16x32_bf16(afl[mt], bfh[nt], a2, 0,0,0);
        a2 = __builtin_amdgcn_mfma_f32_16x16x32_bf16(afh[mt], bfl[nt], a2, 0,0,0);
        a2 = __builtin_amdgcn_mfma_f32_16x16x32_bf16(afh[mt], bfh[nt], a2, 0,0,0);
        acc[mt][nt] = a2;
      }
  }
  #pragma unroll
  for (int mt=0;mt<4;mt++)
    #pragma unroll
    for (int nt=0;nt<4;nt++){
      const int gn = n0 + wn + nt*16 + (L&15);
      const float bvv = bias[gn];
      const int gmb = m0 + wm + mt*16 + (L>>4)*4;
      #pragma unroll
      for (int r=0;r<4;r++){
        const int gm = gmb + r;
        float v = acc[mt][nt][r] + bvv;
        if (mode==0)      o[(size_t)gm*N + gn] = v;
        else if (mode==1) o[(size_t)gm*N + gn] = fmaxf(v, 0.f);
        else {
          const int b = gm>>11, s = gm&2047, h = gn>>6, d = gn&63;
          o[((size_t)(b*NH+h)*SS + s)*DK + d] = v;
        }
      }
    }
}

// -------------------------------------------------- attention row kernel (v8)
// 4 query rows per block, KT layout. Changes vs v7 (LDS-issue bound at 1.9ms):
//  - sq stored f32 [d][4]: one ds_read_b128 broadcast per d + exact cvt at use
//    (was 4x ds_read_b64). Bit-identical scores.
//  - p stored [j][4]: PV reads all 4 rows in one ds_read_b128 (was 4x b32).
//    Same values, same summation order -> bit-identical ctx.
__global__ __launch_bounds__(256) void attn_row(
  const float* __restrict__ q, const float* __restrict__ k, long long qs,
  int bh0, int row0,
  const float* __restrict__ vb, const float* __restrict__ gammas,
  float* __restrict__ att, float* __restrict__ ctx,
  int aw_lo, int aw_hi, int wc)
{
  __shared__ float  sqf[64][4];     // [d][r] q rows (f32; cvt->f64 at use is exact)
  __shared__ float  p4[1024*4];     // [j][r] per-tile staging
  __shared__ double red[4][4];      // [wid][row]
  __shared__ float  cpart[4][4][64];// [row][group][d]
  const int i0 = row0 + blockIdx.x*4;
  const int i3 = i0 + 3;
  const int bh = bh0 + blockIdx.y, h = bh&15, b = bh>>4;
  const int wa = (bh >= aw_lo) && (bh < aw_hi);
  const int t = threadIdx.x, wid = t>>6, L = t&63;
  const double c = softplus64(gammas[h]) * (1.0/21.0);

  {
    const int r = t>>6, d = t&63;
    sqf[d][r] = q[(size_t)blockIdx.y*qs + (size_t)(i0+r)*DK + d];
  }
  const double ce1   = exp(-c);
  const double er    = exp(c);
  const double tstep = exp(-1024.0 * c);
  double u0 = exp(c * (double)(i0 - 4*t));
  double err1 = er, err2 = er*er, err3 = err2*er;
  __syncthreads();

  const float* kb = k + (size_t)blockIdx.y*qs;   // KT base [d][s]
  double sv[4][8];
  double lmax[4] = {-1e300,-1e300,-1e300,-1e300};
  #pragma unroll
  for (int tile=0; tile<2; tile++){
    const int j0 = tile*1024 + 4*t;
    if (j0 <= i3){
      const float* kcol = kb + j0;
      double acc[4][4];
      #pragma unroll
      for (int r=0;r<4;r++)
        #pragma unroll
        for (int e=0;e<4;e++) acc[r][e] = 0.0;
      #pragma unroll 4
      for (int d=0; d<64; d++){
        f32x4 kv = *(const f32x4*)(kcol + (size_t)d*SS);
        f32x4 qv = *(const f32x4*)&sqf[d][0];
        const double k0=(double)kv[0], k1=(double)kv[1];
        const double k2=(double)kv[2], k3=(double)kv[3];
        #pragma unroll
        for (int r=0;r<4;r++){
          const double qd = (double)qv[r];
          acc[r][0] = fma(k0, qd, acc[r][0]);
          acc[r][1] = fma(k1, qd, acc[r][1]);
          acc[r][2] = fma(k2, qd, acc[r][2]);
          acc[r][3] = fma(k3, qd, acc[r][3]);
        }
      }
      #pragma unroll
      for (int r=0;r<4;r++){
        double uu = u0 * ((r==0)?1.0:(r==1)?err1:(r==2)?err2:err3);
        const int ir = i0 + r;
        #pragma unroll
        for (int e=0;e<4;e++){
          const double ef = ((uu < 1e5) ? uu : 1e5) * 0.125;
          const double s = (j0 + e <= ir) ? acc[r][e]*ef : -1e300;
          sv[r][tile*4+e] = s;
          lmax[r] = (lmax[r] > s) ? lmax[r] : s;
          uu *= ce1;
        }
      }
    }
    u0 *= tstep;
  }
  #pragma unroll
  for (int r=0;r<4;r++){
    double lm = lmax[r];
    #pragma unroll
    for (int m2=1;m2<64;m2<<=1){ double o2 = __shfl_xor(lm,m2,64); lm = (lm>o2)?lm:o2; }
    if (L==0) red[wid][r] = lm;
  }
  __syncthreads();
  double m[4];
  #pragma unroll
  for (int r=0;r<4;r++){
    double mm = red[0][r];
    mm = (mm>red[1][r])?mm:red[1][r];
    mm = (mm>red[2][r])?mm:red[2][r];
    mm = (mm>red[3][r])?mm:red[3][r];
    m[r] = mm;
  }
  __syncthreads();

  // exp (f32) + per-row sum
  float ev[4][8];
  double lsum[4] = {0.0,0.0,0.0,0.0};
  #pragma unroll
  for (int tile=0; tile<2; tile++){
    const int j0 = tile*1024 + 4*t;
    if (j0 <= i3){
      #pragma unroll
      for (int r=0;r<4;r++)
        #pragma unroll
        for (int e=0;e<4;e++){
          float ex = expf((float)(sv[r][tile*4+e] - m[r]));
          ev[r][tile*4+e] = ex;
          lsum[r] += (double)ex;
        }
    }
  }
  #pragma unroll
  for (int r=0;r<4;r++){
    double ls = lsum[r];
    #pragma unroll
    for (int m2=1;m2<64;m2<<=1) ls += __shfl_xor(ls,m2,64);
    if (L==0) red[wid][r] = ls;
  }
  __syncthreads();
  float inv[4];
  #pragma unroll
  for (int r=0;r<4;r++)
    inv[r] = (float)(1.0 / (red[0][r]+red[1][r]+red[2][r]+red[3][r]));

  // per-tile: stage p[j][4] (wc), att-write from regs (wa), PV accumulate (wc)
  float ac0[4] = {0.f,0.f,0.f,0.f};
  float ac1[4] = {0.f,0.f,0.f,0.f};
  const int gg = t>>6, d = t&63;
  const float* vr = &vb[(size_t)bh*SS*DK + d];
  #pragma unroll
  for (int tile=0; tile<2; tile++){
    const int base = tile*1024;
    const int j0 = base + 4*t;
    if (wc){
      if (tile) __syncthreads();     // prior tile's PV readers done
      if (j0 <= i3){
        #pragma unroll
        for (int e=0;e<4;e++){
          f32x4 w;
          w[0] = ev[0][tile*4+e]*inv[0]; w[1] = ev[1][tile*4+e]*inv[1];
          w[2] = ev[2][tile*4+e]*inv[2]; w[3] = ev[3][tile*4+e]*inv[3];
          *(f32x4*)&p4[(4*t+e)*4] = w;
        }
      }
      __syncthreads();
    }
    if (wa){
      const int jj = 4*t;
      #pragma unroll
      for (int r=0;r<4;r++){
        const int ir = i0 + r;
        float* rb = &att[((size_t)bh*SS + ir)*SS + base];
        const float iv = inv[r];
        f32x4 o;
        o[0] = (base+jj   <= ir) ? ev[r][tile*4+0]*iv : 0.f;
        o[1] = (base+jj+1 <= ir) ? ev[r][tile*4+1]*iv : 0.f;
        o[2] = (base+jj+2 <= ir) ? ev[r][tile*4+2]*iv : 0.f;
        o[3] = (base+jj+3 <= ir) ? ev[r][tile*4+3]*iv : 0.f;
        *(f32x4*)&rb[jj] = o;
      }
    }
    if (wc){
      int hi = i3 - base; if (hi > 1023) hi = 1023;
      const float* vt = vr + (size_t)base*DK;
      int jj = gg;
      for (; jj+4 <= hi; jj += 8){
        const float v0 = vt[(size_t)jj*DK];
        const float v1 = vt[(size_t)(jj+4)*DK];
        f32x4 pa = *(const f32x4*)&p4[jj*4];
        f32x4 pb = *(const f32x4*)&p4[(jj+4)*4];
        #pragma unroll
        for (int r=0;r<4;r++){
          ac0[r] = fmaf(pa[r], v0, ac0[r]);
          ac1[r] = fmaf(pb[r], v1, ac1[r]);
        }
      }
      for (; jj <= hi; jj += 4){
        const float v0 = vt[(size_t)jj*DK];
        f32x4 pa = *(const f32x4*)&p4[jj*4];
        #pragma unroll
        for (int r=0;r<4;r++) ac0[r] = fmaf(pa[r], v0, ac0[r]);
      }
    }
  }
  if (wc){
    #pragma unroll
    for (int r=0;r<4;r++) cpart[r][gg][d] = ac0[r] + ac1[r];
    __syncthreads();
    {
      const int r = t>>6, dd = t&63;
      const float cc = cpart[r][0][dd]+cpart[r][1][dd]+cpart[r][2][dd]+cpart[r][3][dd];
      ctx[((size_t)(b*SS + (i0+r))*NH + h)*DK + dd] = cc;
    }
  }
}

// -------------------------------------------------- corner: bh63 rows 0..127
// src: [Q slice [s][d] | KT slice [d][s]]   (fallback path only)
__global__ __launch_bounds__(256) void attn_corner(
  const float* __restrict__ src, const float* __restrict__ gammas,
  float* __restrict__ att)
{
  __shared__ float lq[128*64];
  __shared__ float lk[128*64];
  const int t = threadIdx.x;
  for (int idx = t; idx < 128*64; idx += 256)
    lq[idx] = src[idx];                              // Q rows 0..127, [s][d]
  for (int idx = t; idx < 64*128; idx += 256){
    const int d = idx >> 7, s = idx & 127;           // KT[d][s] -> lk[s][d]
    lk[s*64 + d] = src[QKS + (size_t)d*SS + s];
  }
  __syncthreads();
  const double sp = softplus64(gammas[15]);
  const int w = t>>6, L = t&63;
  for (int i = w; i < 128; i += 4){
    double s0 = -1e300, s1 = -1e300;
    if (L <= i){
      double a = 0.0;
      for (int d=0; d<64; d++) a = fma((double)lq[i*64+d], (double)lk[L*64+d], a);
      double eff = exp((double)(i-L)*(1.0/21.0)*sp); eff = (eff<1e5)?eff:1e5;
      s0 = a * 0.125 * eff;
    }
    if (64+L <= i){
      double a = 0.0;
      for (int d=0; d<64; d++) a = fma((double)lq[i*64+d], (double)lk[(64+L)*64+d], a);
      double eff = exp((double)(i-64-L)*(1.0/21.0)*sp); eff = (eff<1e5)?eff:1e5;
      s1 = a * 0.125 * eff;
    }
    double mx = (s0>s1)?s0:s1;
    #pragma unroll
    for (int m2=1;m2<64;m2<<=1){ double o2 = __shfl_xor(mx,m2,64); mx = (mx>o2)?mx:o2; }
    double e0 = (L<=i)    ? exp(s0-mx) : 0.0;
    double e1 = (64+L<=i) ? exp(s1-mx) : 0.0;
    double su = e0+e1;
    #pragma unroll
    for (int m2=1;m2<64;m2<<=1) su += __shfl_xor(su,m2,64);
    const double inv = 1.0/su;
    const float p0 = (float)(e0*inv), p1 = (float)(e1*inv);
    float* rb = &att[((size_t)63*SS + i)*SS];
    #pragma unroll
    for (int tt=0; tt<32; tt++)
      rb[tt*64+L] = (tt==0) ? p0 : (tt==1) ? p1 : 0.f;
  }
}

// -------------------------------------------------- layernorm (f32)
__global__ __launch_bounds__(256) void lnorm(
  const float* __restrict__ a, const float* __restrict__ b,
  const float* __restrict__ sc, const float* __restrict__ bi,
  float* __restrict__ out)
{
  __shared__ float red[4];
  const int row = blockIdx.x, tid = threadIdx.x, wid = tid>>6;
  const size_t rb = (size_t)row*D_MODEL;
  float x[4];
  #pragma unroll
  for (int i=0;i<4;i++){
    const int c = tid + i*256;
    x[i] = a[rb+c] + b[rb+c];
  }
  float s = x[0]+x[1]+x[2]+x[3];
  for (int m2=1;m2<64;m2<<=1) s += __shfl_xor(s,m2,64);
  if ((tid&63)==0) red[wid] = s;
  __syncthreads();
  const float mu = (red[0]+red[1]+red[2]+red[3]) * (1.0f/1024.0f);
  __syncthreads();
  float ss2 = 0.f;
  #pragma unroll
  for (int i=0;i<4;i++){ float d = x[i]-mu; ss2 += d*d; }
  for (int m2=1;m2<64;m2<<=1) ss2 += __shfl_xor(ss2,m2,64);
  if ((tid&63)==0) red[wid] = ss2;
  __syncthreads();
  const float var = (red[0]+red[1]+red[2]+red[3]) * (1.0f/1024.0f);
  const float inv = rsqrtf(var + 1e-5f);
  #pragma unroll
  for (int i=0;i<4;i++){
    const int c = tid + i*256;
    out[rb+c] = (x[i]-mu)*inv*sc[c] + bi[c];
  }
}

// ------------------------------------------------------------------ launch
// If ws_size >= 240 MiB: ALL scratch lives in d_ws; the single attention
// pass fuses ctx + att for all 64 bh (no deferred pass, no copies, no corner).
// Otherwise: fall back to the aliased-into-att schedule (blocks 0-10 scratch,
// 60-63 QF/KF; att bh 11..59 fused, 0..10 deferred, 60..63 staged tail).
extern "C" void kernel_launch(void* const* d_in, const int* in_sizes, int n_in,
                              void* d_out, int out_size, void* d_ws, size_t ws_size,
                              hipStream_t stream)
{
  const float* query  = (const float*)d_in[0];
  const float* key    = (const float*)d_in[1];
  const float* values = (const float*)d_in[2];
  const float* Wk   = (const float*)d_in[3];
  const float* bk   = (const float*)d_in[4];
  const float* Wv   = (const float*)d_in[5];
  const float* bv   = (const float*)d_in[6];
  const float* Wout = (const float*)d_in[7];
  const float* bout = (const float*)d_in[8];
  const float* gammas = (const float*)d_in[9];
  const float* ln1s = (const float*)d_in[10];
  const float* ln1b = (const float*)d_in[11];
  const float* W1   = (const float*)d_in[12];
  const float* b1   = (const float*)d_in[13];
  const float* W2   = (const float*)d_in[14];
  const float* b2   = (const float*)d_in[15];
  const float* ln2s = (const float*)d_in[16];
  const float* ln2b = (const float*)d_in[17];

  float* outx = (float*)d_out;
  float* att  = outx + (size_t)ROWS*D_MODEL;

  const bool usews = (d_ws != nullptr) && (ws_size >= 240ull*MiB);
  char* sc = usews ? (char*)d_ws : (char*)att;
  u16* WkTh  = (u16*)(sc +  0*MiB);
  u16* WkTm  = (u16*)(sc +  2*MiB);
  u16* WkTl  = (u16*)(sc +  4*MiB);
  u16* WvTh  = (u16*)(sc +  6*MiB);
  u16* WvTl  = (u16*)(sc +  8*MiB);
  u16* WoTh  = (u16*)(sc + 10*MiB);
  u16* WoTl  = (u16*)(sc + 12*MiB);
  u16* W1Th  = (u16*)(sc + 14*MiB);
  u16* W1Tl  = (u16*)(sc + 22*MiB);
  u16* W2Th  = (u16*)(sc + 30*MiB);
  u16* W2Tl  = (u16*)(sc + 38*MiB);
  float* vbp  = (float*)(sc +  48*MiB);
  float* ctxb = (float*)(sc +  80*MiB);
  float* aof  = (float*)(sc +  48*MiB);   // reuse after vbp dead
  float* x1f  = (float*)(sc +  80*MiB);   // reuse after ctxb dead
  float* hbuf = (float*)(sc + 112*MiB);
  float* fbuf = (float*)(sc + 144*MiB);
  float* QF = usews ? (float*)(sc + 176*MiB) : att + 60*BHSZ;
  float* KF = usews ? (float*)(sc + 208*MiB) : att + 62*BHSZ;
  float* D1 = att + 63*BHSZ + 2*(MiB/4)*4;
  float* D2 = att + 63*BHSZ;

  dim3 th(256);
  twc<<<dim3(32,32),  th, 0, stream>>>(Wk,   WkTh, WkTm, WkTl, 1024, 1024);
  twc<<<dim3(32,32),  th, 0, stream>>>(Wv,   WvTh, WvTl, nullptr, 1024, 1024);
  twc<<<dim3(32,32),  th, 0, stream>>>(Wout, WoTh, WoTl, nullptr, 1024, 1024);
  twc<<<dim3(128,32), th, 0, stream>>>(W1,   W1Th, W1Tl, nullptr, 1024, 4096);
  twc<<<dim3(32,128), th, 0, stream>>>(W2,   W2Th, W2Tl, nullptr, 4096, 1024);
  gemm3<<<dim3(8,64), th, 0, stream>>>(query, WkTh, WkTm, WkTl, bk, ROWS, 1024, 1024, 0, QF);
  gemm3<<<dim3(8,64), th, 0, stream>>>(key,   WkTh, WkTm, WkTl, bk, ROWS, 1024, 1024, 1, KF);
  gemm2<<<dim3(8,64), th, 0, stream>>>(values, WvTh, WvTl, bv, ROWS, 1024, 1024, 2, vbp);
  if (usews){
    // one fused pass: ctx + att for all 64 bh
    attn_row<<<dim3(SS/4,64), th, 0, stream>>>(QF, KF, (long long)QKS, 0, 0,
                                               vbp, gammas, att, ctxb, 0, 64, 1);
  } else {
    attn_row<<<dim3(SS/4,64), th, 0, stream>>>(QF, KF, (long long)QKS, 0, 0,
                                               vbp, gammas, att, ctxb, 11, 60, 1);
  }
  gemm2<<<dim3(8,64),  th, 0, stream>>>(ctxb, WoTh, WoTl, bout, ROWS, 1024, 1024, 0, aof);
  lnorm<<<dim3(ROWS), th, 0, stream>>>(query, aof, ln1s, ln1b, x1f);
  // FFN, M-chunked x4 so hbuf is 32 MiB
  for (int c = 0; c < 4; ++c){
    gemm2<<<dim3(32,16), th, 0, stream>>>(x1f + (size_t)c*2048*1024, W1Th, W1Tl, b1,
                                          2048, 4096, 1024, 1, hbuf);
    gemm2<<<dim3(8,16),  th, 0, stream>>>(hbuf, W2Th, W2Tl, b2,
                                          2048, 1024, 4096, 0, fbuf + (size_t)c*2048*1024);
  }
  lnorm<<<dim3(ROWS), th, 0, stream>>>(x1f, fbuf, ln2s, ln2b, outx);
  if (!usews){
    // deferred att for bh 0..10 (scratch regions now dead)
    attn_row<<<dim3(SS/4,11), th, 0, stream>>>(QF, KF, (long long)QKS, 0, 0,
                                               vbp, gammas, att, ctxb, 0, 64, 0);
    // bh 60..63 tail: stage q/k slices out of the regions being written
    copyf<<<dim3(512), th, 0, stream>>>(D1,            QF + 60*QKS, 4*(long long)QKS);
    copyf<<<dim3(512), th, 0, stream>>>(D1 + 4*QKS,    KF + 60*QKS, 4*(long long)QKS);
    attn_row<<<dim3(SS/4,3), th, 0, stream>>>(D1, D1 + 4*QKS, (long long)QKS, 60, 0,
                                              vbp, gammas, att, ctxb, 0, 64, 0);
    attn_row<<<dim3(128,1), th, 0, stream>>>(D1 + 3*QKS, D1 + 7*QKS, 0ll, 63, 1536,
                                             vbp, gammas, att, ctxb, 0, 64, 0);
    copyf<<<dim3(128), th, 0, stream>>>(D2,        D1 + 3*QKS, (long long)QKS);
    copyf<<<dim3(128), th, 0, stream>>>(D2 + QKS,  D1 + 7*QKS, (long long)QKS);
    attn_row<<<dim3(352,1), th, 0, stream>>>(D2, D2 + QKS, 0ll, 63, 128,
                                             vbp, gammas, att, ctxb, 0, 64, 0);
    attn_corner<<<dim3(1), th, 0, stream>>>(D2, gammas, att);
  }
}

// Round 11
// 3739.454 us; speedup vs baseline: 2.7499x; 1.1711x over previous
//
#include <hip/hip_runtime.h>
#include <math.h>

typedef unsigned short u16;
typedef float f32x4 __attribute__((ext_vector_type(4)));
typedef short s16x8 __attribute__((ext_vector_type(8)));

#define D_MODEL 1024
#define NH 16
#define DK 64
#define DFF 4096
#define BB 4
#define SS 2048
#define ROWS (BB*SS)   // 8192
#define MiB 1048576ull
#define BHSZ 4194304ull   // floats per att[bh] block (2048*2048)
#define QKS  131072ull    // floats per bh slice of q/k (2048*64)

static __device__ __forceinline__ float bf2f(u16 v){
  union{unsigned u; float f;} x; x.u = ((unsigned)v)<<16; return x.f;
}
static __device__ __forceinline__ u16 f2bf(float f){
  union{float f; unsigned u;} x; x.f=f;
  unsigned r = x.u + 0x7fffu + ((x.u>>16)&1u);
  return (u16)(r>>16);
}
static __device__ __forceinline__ double softplus64(float gf){
  double g = (double)gf;
  return (g > 0.0) ? g + log1p(exp(-g)) : log1p(exp(g));
}

// -------------------------------------------------- transpose + f32->bf16 split
__global__ __launch_bounds__(256) void twc(const float* __restrict__ in,
    u16* __restrict__ oh, u16* __restrict__ om, u16* __restrict__ ol, int R, int C){
  __shared__ float t[32][33];
  int c0 = blockIdx.x*32, r0 = blockIdx.y*32;
  int tx = threadIdx.x & 31, ty = threadIdx.x >> 5;
  for (int i=ty; i<32; i+=8) t[i][tx] = in[(size_t)(r0+i)*C + c0 + tx];
  __syncthreads();
  for (int i=ty; i<32; i+=8){
    float x = t[tx][i];
    u16 h = f2bf(x);
    size_t o = (size_t)(c0+i)*R + r0 + tx;
    oh[o] = h;
    if (om){
      float r1 = x - bf2f(h);
      u16 m = f2bf(r1);
      om[o] = m;
      if (ol){ float r2 = r1 - bf2f(m); ol[o] = f2bf(r2); }
    }
  }
}

// -------------------------------------------------- f32 copy
__global__ __launch_bounds__(256) void copyf(float* __restrict__ dst,
                                             const float* __restrict__ src, long long n){
  long long i = (long long)blockIdx.x*256 + threadIdx.x;
  long long stride = (long long)gridDim.x*256;
  for (; i < n; i += stride) dst[i] = src[i];
}

// -------------------------------------------------- triple-split GEMM (Q/K proj)
// kt=0: o[bh][s][d] layout; kt=1: o[bh][d][s] (K transposed for attn coalescing)
__global__ __launch_bounds__(256) void gemm3(
    const float* __restrict__ A, const u16* __restrict__ Bh,
    const u16* __restrict__ Bm, const u16* __restrict__ Bl,
    const float* __restrict__ bias, int M, int N, int K, int kt, float* __restrict__ o)
{
  __shared__ u16 lAh[128*32], lAm[128*32], lAl[128*32];
  __shared__ u16 lBh[128*32], lBm[128*32], lBl[128*32];
  const int tid = threadIdx.x, wid = tid>>6, L = tid&63;
  const int m0 = blockIdx.y*128, n0 = blockIdx.x*128;
  const int wm = (wid>>1)*64, wn = (wid&1)*64;
  f32x4 acc[4][4] = {};
  const int srow = wid*32 + (L>>2);
  const int scol = (L&3)*8;
  for (int ktile=0; ktile<K; ktile+=32){
    s16x8 ah[2], am[2], al[2], vbh[2], vbm[2], vbl[2];
    #pragma unroll
    for (int rr=0; rr<2; rr++){
      const float* ap = &A[(size_t)(m0 + srow + rr*16)*K + ktile + scol];
      #pragma unroll
      for (int e=0;e<8;e++){
        float x = ap[e];
        u16 hh = f2bf(x); float r1 = x - bf2f(hh);
        u16 mm = f2bf(r1); float r2 = r1 - bf2f(mm);
        ah[rr][e] = (short)hh; am[rr][e] = (short)mm; al[rr][e] = (short)f2bf(r2);
      }
      const size_t bo = (size_t)(n0 + srow + rr*16)*K + ktile + scol;
      vbh[rr] = *(const s16x8*)&Bh[bo];
      vbm[rr] = *(const s16x8*)&Bm[bo];
      vbl[rr] = *(const s16x8*)&Bl[bo];
    }
    __syncthreads();
    #pragma unroll
    for (int rr=0; rr<2; rr++){
      const int ro = (srow + rr*16)*32 + scol;
      *(s16x8*)&lAh[ro] = ah[rr]; *(s16x8*)&lAm[ro] = am[rr]; *(s16x8*)&lAl[ro] = al[rr];
      *(s16x8*)&lBh[ro] = vbh[rr]; *(s16x8*)&lBm[ro] = vbm[rr]; *(s16x8*)&lBl[ro] = vbl[rr];
    }
    __syncthreads();
    const int lro = (L&15)*32 + (L>>4)*8;
    s16x8 afh[4], afm[4], afl[4], bfh[4], bfm[4], bfl[4];
    #pragma unroll
    for (int t=0;t<4;t++){
      afh[t] = *(const s16x8*)&lAh[(wm + t*16)*32 + lro];
      afm[t] = *(const s16x8*)&lAm[(wm + t*16)*32 + lro];
      afl[t] = *(const s16x8*)&lAl[(wm + t*16)*32 + lro];
      bfh[t] = *(const s16x8*)&lBh[(wn + t*16)*32 + lro];
      bfm[t] = *(const s16x8*)&lBm[(wn + t*16)*32 + lro];
      bfl[t] = *(const s16x8*)&lBl[(wn + t*16)*32 + lro];
    }
    #pragma unroll
    for (int mt=0;mt<4;mt++)
      #pragma unroll
      for (int nt=0;nt<4;nt++){
        f32x4 a2 = acc[mt][nt];
        a2 = __builtin_amdgcn_mfma_f32_16x16x32_bf16(afl[mt], bfh[nt], a2, 0,0,0);
        a2 = __builtin_amdgcn_mfma_f32_16x16x32_bf16(afm[mt], bfm[nt], a2, 0,0,0);
        a2 = __builtin_amdgcn_mfma_f32_16x16x32_bf16(afh[mt], bfl[nt], a2, 0,0,0);
        a2 = __builtin_amdgcn_mfma_f32_16x16x32_bf16(afm[mt], bfh[nt], a2, 0,0,0);
        a2 = __builtin_amdgcn_mfma_f32_16x16x32_bf16(afh[mt], bfm[nt], a2, 0,0,0);
        a2 = __builtin_amdgcn_mfma_f32_16x16x32_bf16(afh[mt], bfh[nt], a2, 0,0,0);
        acc[mt][nt] = a2;
      }
  }
  #pragma unroll
  for (int mt=0;mt<4;mt++)
    #pragma unroll
    for (int nt=0;nt<4;nt++){
      const int gn = n0 + wn + nt*16 + (L&15);
      const float bvv = bias[gn];
      const int gmb = m0 + wm + mt*16 + (L>>4)*4;
      const int h = gn>>6, d = gn&63;
      #pragma unroll
      for (int r=0;r<4;r++){
        const int gm = gmb + r, b = gm>>11, s = gm&2047;
        const float v = acc[mt][nt][r] + bvv;
        if (kt) o[((size_t)(b*NH+h)*DK + d)*SS + s] = v;
        else    o[((size_t)(b*NH+h)*SS + s)*DK + d] = v;
      }
    }
}

// -------------------------------------------------- pair-split GEMM (~f32 quality)
// mode 0: o[gm][gn]; 1: relu; 2: [bh][s][d] scatter (vbp f32);
// mode 3: bf16 h/l split scatter to Vh/Vl at [bh][d][s]  (o = Vh base; Vl = Vh+16MiB)
__global__ __launch_bounds__(256) void gemm2(
    const float* __restrict__ A, const u16* __restrict__ Bh, const u16* __restrict__ Bl,
    const float* __restrict__ bias, int M, int N, int K, int mode, float* __restrict__ o)
{
  __shared__ u16 lAh[128*32], lAl[128*32], lBh[128*32], lBl[128*32];
  const int tid = threadIdx.x, wid = tid>>6, L = tid&63;
  const int m0 = blockIdx.y*128, n0 = blockIdx.x*128;
  const int wm = (wid>>1)*64, wn = (wid&1)*64;
  f32x4 acc[4][4] = {};
  const int srow = wid*32 + (L>>2);
  const int scol = (L&3)*8;
  for (int kt=0; kt<K; kt+=32){
    s16x8 ah[2], al[2], vbh[2], vbl[2];
    #pragma unroll
    for (int rr=0; rr<2; rr++){
      const float* ap = &A[(size_t)(m0 + srow + rr*16)*K + kt + scol];
      #pragma unroll
      for (int e=0;e<8;e++){
        float x = ap[e];
        u16 hh = f2bf(x);
        ah[rr][e] = (short)hh;
        al[rr][e] = (short)f2bf(x - bf2f(hh));
      }
      const size_t bo = (size_t)(n0 + srow + rr*16)*K + kt + scol;
      vbh[rr] = *(const s16x8*)&Bh[bo];
      vbl[rr] = *(const s16x8*)&Bl[bo];
    }
    __syncthreads();
    #pragma unroll
    for (int rr=0; rr<2; rr++){
      const int ro = (srow + rr*16)*32 + scol;
      *(s16x8*)&lAh[ro] = ah[rr]; *(s16x8*)&lAl[ro] = al[rr];
      *(s16x8*)&lBh[ro] = vbh[rr]; *(s16x8*)&lBl[ro] = vbl[rr];
    }
    __syncthreads();
    const int lro = (L&15)*32 + (L>>4)*8;
    s16x8 afh[4], afl[4], bfh[4], bfl[4];
    #pragma unroll
    for (int t=0;t<4;t++){
      afh[t] = *(const s16x8*)&lAh[(wm + t*16)*32 + lro];
      afl[t] = *(const s16x8*)&lAl[(wm + t*16)*32 + lro];
      bfh[t] = *(const s16x8*)&lBh[(wn + t*16)*32 + lro];
      bfl[t] = *(const s16x8*)&lBl[(wn + t*16)*32 + lro];
    }
    #pragma unroll
    for (int mt=0;mt<4;mt++)
      #pragma unroll
      for (int nt=0;nt<4;nt++){
        f32x4 a2 = acc[mt][nt];
        a2 = __builtin_amdgcn_mfma_f32_16x16x32_bf16(afl[mt], bfh[nt], a2, 0,0,0);
        a2 = __builtin_amdgcn_mfma_f32_16x16x32_bf16(afh[mt], bfl[nt], a2, 0,0,0);
        a2 = __builtin_amdgcn_mfma_f32_16x16x32_bf16(afh[mt], bfh[nt], a2, 0,0,0);
        acc[mt][nt] = a2;
      }
  }
  #pragma unroll
  for (int mt=0;mt<4;mt++)
    #pragma unroll
    for (int nt=0;nt<4;nt++){
      const int gn = n0 + wn + nt*16 + (L&15);
      const float bvv = bias[gn];
      const int gmb = m0 + wm + mt*16 + (L>>4)*4;
      #pragma unroll
      for (int r=0;r<4;r++){
        const int gm = gmb + r;
        float v = acc[mt][nt][r] + bvv;
        if (mode==0)      o[(size_t)gm*N + gn] = v;
        else if (mode==1) o[(size_t)gm*N + gn] = fmaxf(v, 0.f);
        else if (mode==3){
          const int b = gm>>11, s = gm&2047, h = gn>>6, d = gn&63;
          u16* vh = (u16*)o;
          u16* vl = vh + 8388608ull;   // +16 MiB in u16
          const size_t off = ((size_t)(b*NH+h)*DK + d)*SS + s;
          const u16 hh = f2bf(v);
          vh[off] = hh;
          vl[off] = f2bf(v - bf2f(hh));
        } else {
          const int b = gm>>11, s = gm&2047, h = gn>>6, d = gn&63;
          o[((size_t)(b*NH+h)*SS + s)*DK + d] = v;
        }
      }
    }
}

// -------------------------------------------------- attn score kernel (v9, usews)
// Score + softmax + att write ONLY (PV moved to pvg MFMA kernel).
// LDS ~1.3KB -> occupancy VGPR-bound (~8 waves/SIMD). 4 rows/block, KT layout.
__global__ __launch_bounds__(256) void attn_sc(
  const float* __restrict__ q, const float* __restrict__ k,
  const float* __restrict__ gammas, float* __restrict__ att)
{
  __shared__ float  sqf[64][4];     // [d][r]
  __shared__ double red[4][4];      // [wid][row]
  const int i0 = blockIdx.x*4;
  const int i3 = i0 + 3;
  const int bh = blockIdx.y, h = bh&15;
  const int t = threadIdx.x, wid = t>>6, L = t&63;
  const double c = softplus64(gammas[h]) * (1.0/21.0);

  {
    const int r = t>>6, d = t&63;
    sqf[d][r] = q[(size_t)bh*QKS + (size_t)(i0+r)*DK + d];
  }
  const double ce1   = exp(-c);
  const double er    = exp(c);
  const double tstep = exp(-1024.0 * c);
  double u0 = exp(c * (double)(i0 - 4*t));
  double err1 = er, err2 = er*er, err3 = err2*er;
  __syncthreads();

  const float* kb = k + (size_t)bh*QKS;   // KT base [d][s]
  double sv[4][8];
  double lmax[4] = {-1e300,-1e300,-1e300,-1e300};
  #pragma unroll
  for (int tile=0; tile<2; tile++){
    const int j0 = tile*1024 + 4*t;
    if (j0 <= i3){
      const float* kcol = kb + j0;
      double acc[4][4];
      #pragma unroll
      for (int r=0;r<4;r++)
        #pragma unroll
        for (int e=0;e<4;e++) acc[r][e] = 0.0;
      #pragma unroll 4
      for (int d=0; d<64; d++){
        f32x4 kv = *(const f32x4*)(kcol + (size_t)d*SS);
        f32x4 qv = *(const f32x4*)&sqf[d][0];
        const double k0=(double)kv[0], k1=(double)kv[1];
        const double k2=(double)kv[2], k3=(double)kv[3];
        #pragma unroll
        for (int r=0;r<4;r++){
          const double qd = (double)qv[r];
          acc[r][0] = fma(k0, qd, acc[r][0]);
          acc[r][1] = fma(k1, qd, acc[r][1]);
          acc[r][2] = fma(k2, qd, acc[r][2]);
          acc[r][3] = fma(k3, qd, acc[r][3]);
        }
      }
      #pragma unroll
      for (int r=0;r<4;r++){
        double uu = u0 * ((r==0)?1.0:(r==1)?err1:(r==2)?err2:err3);
        const int ir = i0 + r;
        #pragma unroll
        for (int e=0;e<4;e++){
          const double ef = ((uu < 1e5) ? uu : 1e5) * 0.125;
          const double s = (j0 + e <= ir) ? acc[r][e]*ef : -1e300;
          sv[r][tile*4+e] = s;
          lmax[r] = (lmax[r] > s) ? lmax[r] : s;
          uu *= ce1;
        }
      }
    }
    u0 *= tstep;
  }
  #pragma unroll
  for (int r=0;r<4;r++){
    double lm = lmax[r];
    #pragma unroll
    for (int m2=1;m2<64;m2<<=1){ double o2 = __shfl_xor(lm,m2,64); lm = (lm>o2)?lm:o2; }
    if (L==0) red[wid][r] = lm;
  }
  __syncthreads();
  double m[4];
  #pragma unroll
  for (int r=0;r<4;r++){
    double mm = red[0][r];
    mm = (mm>red[1][r])?mm:red[1][r];
    mm = (mm>red[2][r])?mm:red[2][r];
    mm = (mm>red[3][r])?mm:red[3][r];
    m[r] = mm;
  }
  __syncthreads();

  float ev[4][8];
  double lsum[4] = {0.0,0.0,0.0,0.0};
  #pragma unroll
  for (int tile=0; tile<2; tile++){
    const int j0 = tile*1024 + 4*t;
    if (j0 <= i3){
      #pragma unroll
      for (int r=0;r<4;r++)
        #pragma unroll
        for (int e=0;e<4;e++){
          float ex = expf((float)(sv[r][tile*4+e] - m[r]));
          ev[r][tile*4+e] = ex;
          lsum[r] += (double)ex;
        }
    }
  }
  #pragma unroll
  for (int r=0;r<4;r++){
    double ls = lsum[r];
    #pragma unroll
    for (int m2=1;m2<64;m2<<=1) ls += __shfl_xor(ls,m2,64);
    if (L==0) red[wid][r] = ls;
  }
  __syncthreads();
  float inv[4];
  #pragma unroll
  for (int r=0;r<4;r++)
    inv[r] = (float)(1.0 / (red[0][r]+red[1][r]+red[2][r]+red[3][r]));

  #pragma unroll
  for (int tile=0; tile<2; tile++){
    const int base = tile*1024;
    const int jj = 4*t;
    #pragma unroll
    for (int r=0;r<4;r++){
      const int ir = i0 + r;
      float* rb = &att[((size_t)bh*SS + ir)*SS + base];
      const float iv = inv[r];
      f32x4 o;
      o[0] = (base+jj   <= ir) ? ev[r][tile*4+0]*iv : 0.f;
      o[1] = (base+jj+1 <= ir) ? ev[r][tile*4+1]*iv : 0.f;
      o[2] = (base+jj+2 <= ir) ? ev[r][tile*4+2]*iv : 0.f;
      o[3] = (base+jj+3 <= ir) ? ev[r][tile*4+3]*iv : 0.f;
      *(f32x4*)&rb[jj] = o;
    }
  }
}

// -------------------------------------------------- PV as causal MFMA GEMM (usews)
// ctx[bh][i][d] = sum_{j<=i} att[bh][i][j] * V[bh][j][d].
// A = att (f32, split in-kernel), B = Vh/Vl u16 [bh][d][s] (pre-split, mode-3).
// Tile: BM=128, N=64(=DK), BK=32; K-limit = m0+128 (att zero-padded above diag).
__global__ __launch_bounds__(256) void pvg(
  const float* __restrict__ att, const u16* __restrict__ Vh, const u16* __restrict__ Vl,
  float* __restrict__ ctx)
{
  __shared__ u16 lAh[128*32], lAl[128*32], lBh[64*32], lBl[64*32];
  const int tid = threadIdx.x, wid = tid>>6, L = tid&63;
  const int bh = blockIdx.y, m0 = blockIdx.x*128;
  const int b = bh>>4, h = bh&15;
  const float* A  = att + (size_t)bh*BHSZ;
  const u16*  Bhp = Vh + (size_t)bh*DK*SS;
  const u16*  Blp = Vl + (size_t)bh*DK*SS;
  const int wm = wid*32;
  f32x4 acc[2][4] = {};
  const int srow = wid*32 + (L>>2);   // 0..111 (+16 via rr)
  const int scol = (L&3)*8;
  const int db   = tid>>2;            // 0..63 (B row = d)
  const int scb  = (tid&3)*8;
  const int Klim = m0 + 128;
  for (int kt=0; kt<Klim; kt+=32){
    s16x8 ah[2], al[2], vh8, vl8;
    #pragma unroll
    for (int rr=0; rr<2; rr++){
      const float* ap = &A[(size_t)(m0 + srow + rr*16)*SS + kt + scol];
      #pragma unroll
      for (int e=0;e<8;e++){
        float x = ap[e];
        u16 hh = f2bf(x);
        ah[rr][e] = (short)hh;
        al[rr][e] = (short)f2bf(x - bf2f(hh));
      }
    }
    {
      const size_t bo = (size_t)db*SS + kt + scb;
      vh8 = *(const s16x8*)&Bhp[bo];
      vl8 = *(const s16x8*)&Blp[bo];
    }
    __syncthreads();
    #pragma unroll
    for (int rr=0; rr<2; rr++){
      const int ro = (srow + rr*16)*32 + scol;
      *(s16x8*)&lAh[ro] = ah[rr]; *(s16x8*)&lAl[ro] = al[rr];
    }
    *(s16x8*)&lBh[db*32 + scb] = vh8;
    *(s16x8*)&lBl[db*32 + scb] = vl8;
    __syncthreads();
    const int lro = (L&15)*32 + (L>>4)*8;
    s16x8 afh[2], afl[2], bfh[4], bfl[4];
    #pragma unroll
    for (int mt=0;mt<2;mt++){
      afh[mt] = *(const s16x8*)&lAh[(wm + mt*16)*32 + lro];
      afl[mt] = *(const s16x8*)&lAl[(wm + mt*16)*32 + lro];
    }
    #pragma unroll
    for (int nt=0;nt<4;nt++){
      bfh[nt] = *(const s16x8*)&lBh[(nt*16)*32 + lro];
      bfl[nt] = *(const s16x8*)&lBl[(nt*16)*32 + lro];
    }
    #pragma unroll
    for (int mt=0;mt<2;mt++)
      #pragma unroll
      for (int nt=0;nt<4;nt++){
        f32x4 a2 = acc[mt][nt];
        a2 = __builtin_amdgcn_mfma_f32_16x16x32_bf16(afl[mt], bfh[nt], a2, 0,0,0);
        a2 = __builtin_amdgcn_mfma_f32_16x16x32_bf16(afh[mt], bfl[nt], a2, 0,0,0);
        a2 = __builtin_amdgcn_mfma_f32_16x16x32_bf16(afh[mt], bfh[nt], a2, 0,0,0);
        acc[mt][nt] = a2;
      }
  }
  #pragma unroll
  for (int mt=0;mt<2;mt++)
    #pragma unroll
    for (int nt=0;nt<4;nt++){
      const int d = nt*16 + (L&15);
      const int gmb = m0 + wm + mt*16 + (L>>4)*4;
      #pragma unroll
      for (int r=0;r<4;r++){
        const int s = gmb + r;
        ctx[((size_t)(b*SS + s)*NH + h)*DK + d] = acc[mt][nt][r];
      }
    }
}

// -------------------------------------------------- attention row kernel (v8, fallback)
__global__ __launch_bounds__(256) void attn_row(
  const float* __restrict__ q, const float* __restrict__ k, long long qs,
  int bh0, int row0,
  const float* __restrict__ vb, const float* __restrict__ gammas,
  float* __restrict__ att, float* __restrict__ ctx,
  int aw_lo, int aw_hi, int wc)
{
  __shared__ float  sqf[64][4];
  __shared__ float  p4[1024*4];
  __shared__ double red[4][4];
  __shared__ float  cpart[4][4][64];
  const int i0 = row0 + blockIdx.x*4;
  const int i3 = i0 + 3;
  const int bh = bh0 + blockIdx.y, h = bh&15, b = bh>>4;
  const int wa = (bh >= aw_lo) && (bh < aw_hi);
  const int t = threadIdx.x, wid = t>>6, L = t&63;
  const double c = softplus64(gammas[h]) * (1.0/21.0);

  {
    const int r = t>>6, d = t&63;
    sqf[d][r] = q[(size_t)blockIdx.y*qs + (size_t)(i0+r)*DK + d];
  }
  const double ce1   = exp(-c);
  const double er    = exp(c);
  const double tstep = exp(-1024.0 * c);
  double u0 = exp(c * (double)(i0 - 4*t));
  double err1 = er, err2 = er*er, err3 = err2*er;
  __syncthreads();

  const float* kb = k + (size_t)blockIdx.y*qs;
  double sv[4][8];
  double lmax[4] = {-1e300,-1e300,-1e300,-1e300};
  #pragma unroll
  for (int tile=0; tile<2; tile++){
    const int j0 = tile*1024 + 4*t;
    if (j0 <= i3){
      const float* kcol = kb + j0;
      double acc[4][4];
      #pragma unroll
      for (int r=0;r<4;r++)
        #pragma unroll
        for (int e=0;e<4;e++) acc[r][e] = 0.0;
      #pragma unroll 4
      for (int d=0; d<64; d++){
        f32x4 kv = *(const f32x4*)(kcol + (size_t)d*SS);
        f32x4 qv = *(const f32x4*)&sqf[d][0];
        const double k0=(double)kv[0], k1=(double)kv[1];
        const double k2=(double)kv[2], k3=(double)kv[3];
        #pragma unroll
        for (int r=0;r<4;r++){
          const double qd = (double)qv[r];
          acc[r][0] = fma(k0, qd, acc[r][0]);
          acc[r][1] = fma(k1, qd, acc[r][1]);
          acc[r][2] = fma(k2, qd, acc[r][2]);
          acc[r][3] = fma(k3, qd, acc[r][3]);
        }
      }
      #pragma unroll
      for (int r=0;r<4;r++){
        double uu = u0 * ((r==0)?1.0:(r==1)?err1:(r==2)?err2:err3);
        const int ir = i0 + r;
        #pragma unroll
        for (int e=0;e<4;e++){
          const double ef = ((uu < 1e5) ? uu : 1e5) * 0.125;
          const double s = (j0 + e <= ir) ? acc[r][e]*ef : -1e300;
          sv[r][tile*4+e] = s;
          lmax[r] = (lmax[r] > s) ? lmax[r] : s;
          uu *= ce1;
        }
      }
    }
    u0 *= tstep;
  }
  #pragma unroll
  for (int r=0;r<4;r++){
    double lm = lmax[r];
    #pragma unroll
    for (int m2=1;m2<64;m2<<=1){ double o2 = __shfl_xor(lm,m2,64); lm = (lm>o2)?lm:o2; }
    if (L==0) red[wid][r] = lm;
  }
  __syncthreads();
  double m[4];
  #pragma unroll
  for (int r=0;r<4;r++){
    double mm = red[0][r];
    mm = (mm>red[1][r])?mm:red[1][r];
    mm = (mm>red[2][r])?mm:red[2][r];
    mm = (mm>red[3][r])?mm:red[3][r];
    m[r] = mm;
  }
  __syncthreads();

  float ev[4][8];
  double lsum[4] = {0.0,0.0,0.0,0.0};
  #pragma unroll
  for (int tile=0; tile<2; tile++){
    const int j0 = tile*1024 + 4*t;
    if (j0 <= i3){
      #pragma unroll
      for (int r=0;r<4;r++)
        #pragma unroll
        for (int e=0;e<4;e++){
          float ex = expf((float)(sv[r][tile*4+e] - m[r]));
          ev[r][tile*4+e] = ex;
          lsum[r] += (double)ex;
        }
    }
  }
  #pragma unroll
  for (int r=0;r<4;r++){
    double ls = lsum[r];
    #pragma unroll
    for (int m2=1;m2<64;m2<<=1) ls += __shfl_xor(ls,m2,64);
    if (L==0) red[wid][r] = ls;
  }
  __syncthreads();
  float inv[4];
  #pragma unroll
  for (int r=0;r<4;r++)
    inv[r] = (float)(1.0 / (red[0][r]+red[1][r]+red[2][r]+red[3][r]));

  float ac0[4] = {0.f,0.f,0.f,0.f};
  float ac1[4] = {0.f,0.f,0.f,0.f};
  const int gg = t>>6, d = t&63;
  const float* vr = &vb[(size_t)bh*SS*DK + d];
  #pragma unroll
  for (int tile=0; tile<2; tile++){
    const int base = tile*1024;
    const int j0 = base + 4*t;
    if (wc){
      if (tile) __syncthreads();
      if (j0 <= i3){
        #pragma unroll
        for (int e=0;e<4;e++){
          f32x4 w;
          w[0] = ev[0][tile*4+e]*inv[0]; w[1] = ev[1][tile*4+e]*inv[1];
          w[2] = ev[2][tile*4+e]*inv[2]; w[3] = ev[3][tile*4+e]*inv[3];
          *(f32x4*)&p4[(4*t+e)*4] = w;
        }
      }
      __syncthreads();
    }
    if (wa){
      const int jj = 4*t;
      #pragma unroll
      for (int r=0;r<4;r++){
        const int ir = i0 + r;
        float* rb = &att[((size_t)bh*SS + ir)*SS + base];
        const float iv = inv[r];
        f32x4 o;
        o[0] = (base+jj   <= ir) ? ev[r][tile*4+0]*iv : 0.f;
        o[1] = (base+jj+1 <= ir) ? ev[r][tile*4+1]*iv : 0.f;
        o[2] = (base+jj+2 <= ir) ? ev[r][tile*4+2]*iv : 0.f;
        o[3] = (base+jj+3 <= ir) ? ev[r][tile*4+3]*iv : 0.f;
        *(f32x4*)&rb[jj] = o;
      }
    }
    if (wc){
      int hi = i3 - base; if (hi > 1023) hi = 1023;
      const float* vt = vr + (size_t)base*DK;
      int jj = gg;
      for (; jj+4 <= hi; jj += 8){
        const float v0 = vt[(size_t)jj*DK];
        const float v1 = vt[(size_t)(jj+4)*DK];
        f32x4 pa = *(const f32x4*)&p4[jj*4];
        f32x4 pb = *(const f32x4*)&p4[(jj+4)*4];
        #pragma unroll
        for (int r=0;r<4;r++){
          ac0[r] = fmaf(pa[r], v0, ac0[r]);
          ac1[r] = fmaf(pb[r], v1, ac1[r]);
        }
      }
      for (; jj <= hi; jj += 4){
        const float v0 = vt[(size_t)jj*DK];
        f32x4 pa = *(const f32x4*)&p4[jj*4];
        #pragma unroll
        for (int r=0;r<4;r++) ac0[r] = fmaf(pa[r], v0, ac0[r]);
      }
    }
  }
  if (wc){
    #pragma unroll
    for (int r=0;r<4;r++) cpart[r][gg][d] = ac0[r] + ac1[r];
    __syncthreads();
    {
      const int r = t>>6, dd = t&63;
      const float cc = cpart[r][0][dd]+cpart[r][1][dd]+cpart[r][2][dd]+cpart[r][3][dd];
      ctx[((size_t)(b*SS + (i0+r))*NH + h)*DK + dd] = cc;
    }
  }
}

// -------------------------------------------------- corner: bh63 rows 0..127 (fallback)
__global__ __launch_bounds__(256) void attn_corner(
  const float* __restrict__ src, const float* __restrict__ gammas,
  float* __restrict__ att)
{
  __shared__ float lq[128*64];
  __shared__ float lk[128*64];
  const int t = threadIdx.x;
  for (int idx = t; idx < 128*64; idx += 256)
    lq[idx] = src[idx];
  for (int idx = t; idx < 64*128; idx += 256){
    const int d = idx >> 7, s = idx & 127;
    lk[s*64 + d] = src[QKS + (size_t)d*SS + s];
  }
  __syncthreads();
  const double sp = softplus64(gammas[15]);
  const int w = t>>6, L = t&63;
  for (int i = w; i < 128; i += 4){
    double s0 = -1e300, s1 = -1e300;
    if (L <= i){
      double a = 0.0;
      for (int d=0; d<64; d++) a = fma((double)lq[i*64+d], (double)lk[L*64+d], a);
      double eff = exp((double)(i-L)*(1.0/21.0)*sp); eff = (eff<1e5)?eff:1e5;
      s0 = a * 0.125 * eff;
    }
    if (64+L <= i){
      double a = 0.0;
      for (int d=0; d<64; d++) a = fma((double)lq[i*64+d], (double)lk[(64+L)*64+d], a);
      double eff = exp((double)(i-64-L)*(1.0/21.0)*sp); eff = (eff<1e5)?eff:1e5;
      s1 = a * 0.125 * eff;
    }
    double mx = (s0>s1)?s0:s1;
    #pragma unroll
    for (int m2=1;m2<64;m2<<=1){ double o2 = __shfl_xor(mx,m2,64); mx = (mx>o2)?mx:o2; }
    double e0 = (L<=i)    ? exp(s0-mx) : 0.0;
    double e1 = (64+L<=i) ? exp(s1-mx) : 0.0;
    double su = e0+e1;
    #pragma unroll
    for (int m2=1;m2<64;m2<<=1) su += __shfl_xor(su,m2,64);
    const double inv = 1.0/su;
    const float p0 = (float)(e0*inv), p1 = (float)(e1*inv);
    float* rb = &att[((size_t)63*SS + i)*SS];
    #pragma unroll
    for (int tt=0; tt<32; tt++)
      rb[tt*64+L] = (tt==0) ? p0 : (tt==1) ? p1 : 0.f;
  }
}

// -------------------------------------------------- layernorm (f32)
__global__ __launch_bounds__(256) void lnorm(
  const float* __restrict__ a, const float* __restrict__ b,
  const float* __restrict__ sc, const float* __restrict__ bi,
  float* __restrict__ out)
{
  __shared__ float red[4];
  const int row = blockIdx.x, tid = threadIdx.x, wid = tid>>6;
  const size_t rb = (size_t)row*D_MODEL;
  float x[4];
  #pragma unroll
  for (int i=0;i<4;i++){
    const int c = tid + i*256;
    x[i] = a[rb+c] + b[rb+c];
  }
  float s = x[0]+x[1]+x[2]+x[3];
  for (int m2=1;m2<64;m2<<=1) s += __shfl_xor(s,m2,64);
  if ((tid&63)==0) red[wid] = s;
  __syncthreads();
  const float mu = (red[0]+red[1]+red[2]+red[3]) * (1.0f/1024.0f);
  __syncthreads();
  float ss2 = 0.f;
  #pragma unroll
  for (int i=0;i<4;i++){ float d = x[i]-mu; ss2 += d*d; }
  for (int m2=1;m2<64;m2<<=1) ss2 += __shfl_xor(ss2,m2,64);
  if ((tid&63)==0) red[wid] = ss2;
  __syncthreads();
  const float var = (red[0]+red[1]+red[2]+red[3]) * (1.0f/1024.0f);
  const float inv = rsqrtf(var + 1e-5f);
  #pragma unroll
  for (int i=0;i<4;i++){
    const int c = tid + i*256;
    out[rb+c] = (x[i]-mu)*inv*sc[c] + bi[c];
  }
}

// ------------------------------------------------------------------ launch
// usews (ws >= 240 MiB): V-proj writes bf16 Vh/Vl [bh][d][s] into the old vbp
// slot (48..80 MiB); attn_sc computes score+softmax+att for all 64 bh at high
// occupancy; pvg computes ctx = att x V via causal MFMA GEMM.
// Fallback (< 240 MiB): exact round-10 schedule.
extern "C" void kernel_launch(void* const* d_in, const int* in_sizes, int n_in,
                              void* d_out, int out_size, void* d_ws, size_t ws_size,
                              hipStream_t stream)
{
  const float* query  = (const float*)d_in[0];
  const float* key    = (const float*)d_in[1];
  const float* values = (const float*)d_in[2];
  const float* Wk   = (const float*)d_in[3];
  const float* bk   = (const float*)d_in[4];
  const float* Wv   = (const float*)d_in[5];
  const float* bv   = (const float*)d_in[6];
  const float* Wout = (const float*)d_in[7];
  const float* bout = (const float*)d_in[8];
  const float* gammas = (const float*)d_in[9];
  const float* ln1s = (const float*)d_in[10];
  const float* ln1b = (const float*)d_in[11];
  const float* W1   = (const float*)d_in[12];
  const float* b1   = (const float*)d_in[13];
  const float* W2   = (const float*)d_in[14];
  const float* b2   = (const float*)d_in[15];
  const float* ln2s = (const float*)d_in[16];
  const float* ln2b = (const float*)d_in[17];

  float* outx = (float*)d_out;
  float* att  = outx + (size_t)ROWS*D_MODEL;

  const bool usews = (d_ws != nullptr) && (ws_size >= 240ull*MiB);
  char* sc = usews ? (char*)d_ws : (char*)att;
  u16* WkTh  = (u16*)(sc +  0*MiB);
  u16* WkTm  = (u16*)(sc +  2*MiB);
  u16* WkTl  = (u16*)(sc +  4*MiB);
  u16* WvTh  = (u16*)(sc +  6*MiB);
  u16* WvTl  = (u16*)(sc +  8*MiB);
  u16* WoTh  = (u16*)(sc + 10*MiB);
  u16* WoTl  = (u16*)(sc + 12*MiB);
  u16* W1Th  = (u16*)(sc + 14*MiB);
  u16* W1Tl  = (u16*)(sc + 22*MiB);
  u16* W2Th  = (u16*)(sc + 30*MiB);
  u16* W2Tl  = (u16*)(sc + 38*MiB);
  float* vbp  = (float*)(sc +  48*MiB);   // fallback: f32 V. usews: Vh(48)/Vl(64)
  float* ctxb = (float*)(sc +  80*MiB);
  float* aof  = (float*)(sc +  48*MiB);   // reuse after vbp/Vh dead
  float* x1f  = (float*)(sc +  80*MiB);   // reuse after ctxb dead
  float* hbuf = (float*)(sc + 112*MiB);
  float* fbuf = (float*)(sc + 144*MiB);
  float* QF = usews ? (float*)(sc + 176*MiB) : att + 60*BHSZ;
  float* KF = usews ? (float*)(sc + 208*MiB) : att + 62*BHSZ;
  float* D1 = att + 63*BHSZ + 2*(MiB/4)*4;
  float* D2 = att + 63*BHSZ;

  dim3 th(256);
  twc<<<dim3(32,32),  th, 0, stream>>>(Wk,   WkTh, WkTm, WkTl, 1024, 1024);
  twc<<<dim3(32,32),  th, 0, stream>>>(Wv,   WvTh, WvTl, nullptr, 1024, 1024);
  twc<<<dim3(32,32),  th, 0, stream>>>(Wout, WoTh, WoTl, nullptr, 1024, 1024);
  twc<<<dim3(128,32), th, 0, stream>>>(W1,   W1Th, W1Tl, nullptr, 1024, 4096);
  twc<<<dim3(32,128), th, 0, stream>>>(W2,   W2Th, W2Tl, nullptr, 4096, 1024);
  gemm3<<<dim3(8,64), th, 0, stream>>>(query, WkTh, WkTm, WkTl, bk, ROWS, 1024, 1024, 0, QF);
  gemm3<<<dim3(8,64), th, 0, stream>>>(key,   WkTh, WkTm, WkTl, bk, ROWS, 1024, 1024, 1, KF);
  if (usews){
    // V projection -> bf16 split Vh/Vl at [bh][d][s]
    gemm2<<<dim3(8,64), th, 0, stream>>>(values, WvTh, WvTl, bv, ROWS, 1024, 1024, 3, vbp);
    // score + softmax + att for all 64 bh (high occupancy, no PV)
    attn_sc<<<dim3(SS/4,64), th, 0, stream>>>(QF, KF, gammas, att);
    // ctx = att x V via causal MFMA GEMM
    pvg<<<dim3(16,64), th, 0, stream>>>(att, (const u16*)vbp,
                                        (const u16*)vbp + 8388608ull, ctxb);
  } else {
    gemm2<<<dim3(8,64), th, 0, stream>>>(values, WvTh, WvTl, bv, ROWS, 1024, 1024, 2, vbp);
    attn_row<<<dim3(SS/4,64), th, 0, stream>>>(QF, KF, (long long)QKS, 0, 0,
                                               vbp, gammas, att, ctxb, 11, 60, 1);
  }
  gemm2<<<dim3(8,64),  th, 0, stream>>>(ctxb, WoTh, WoTl, bout, ROWS, 1024, 1024, 0, aof);
  lnorm<<<dim3(ROWS), th, 0, stream>>>(query, aof, ln1s, ln1b, x1f);
  for (int c = 0; c < 4; ++c){
    gemm2<<<dim3(32,16), th, 0, stream>>>(x1f + (size_t)c*2048*1024, W1Th, W1Tl, b1,
                                          2048, 4096, 1024, 1, hbuf);
    gemm2<<<dim3(8,16),  th, 0, stream>>>(hbuf, W2Th, W2Tl, b2,
                                          2048, 1024, 4096, 0, fbuf + (size_t)c*2048*1024);
  }
  lnorm<<<dim3(ROWS), th, 0, stream>>>(x1f, fbuf, ln2s, ln2b, outx);
  if (!usews){
    attn_row<<<dim3(SS/4,11), th, 0, stream>>>(QF, KF, (long long)QKS, 0, 0,
                                               vbp, gammas, att, ctxb, 0, 64, 0);
    copyf<<<dim3(512), th, 0, stream>>>(D1,            QF + 60*QKS, 4*(long long)QKS);
    copyf<<<dim3(512), th, 0, stream>>>(D1 + 4*QKS,    KF + 60*QKS, 4*(long long)QKS);
    attn_row<<<dim3(SS/4,3), th, 0, stream>>>(D1, D1 + 4*QKS, (long long)QKS, 60, 0,
                                              vbp, gammas, att, ctxb, 0, 64, 0);
    attn_row<<<dim3(128,1), th, 0, stream>>>(D1 + 3*QKS, D1 + 7*QKS, 0ll, 63, 1536,
                                             vbp, gammas, att, ctxb, 0, 64, 0);
    copyf<<<dim3(128), th, 0, stream>>>(D2,        D1 + 3*QKS, (long long)QKS);
    copyf<<<dim3(128), th, 0, stream>>>(D2 + QKS,  D1 + 7*QKS, (long long)QKS);
    attn_row<<<dim3(352,1), th, 0, stream>>>(D2, D2 + QKS, 0ll, 63, 128,
                                             vbp, gammas, att, ctxb, 0, 64, 0);
    attn_corner<<<dim3(1), th, 0, stream>>>(D2, gammas, att);
  }
}